// Round 11
// baseline (294.310 us; speedup 1.0000x reference)
//
#include <hip/hip_runtime.h>
#include <hip/hip_bf16.h>
#include <math.h>

// ---------------------------------------------------------------------------
// Shapes (compile-time constants for this problem)
// ---------------------------------------------------------------------------
#define SEQ     2048
#define D_MODEL 1024
#define D_IN    2048
#define N_STATE 16
#define DT_RANK 64
#define XDBL_W  96          // DT_RANK + 2*N_STATE
#define XDBL_LD 128         // padded leading dim of x_dbl
#define LC      64          // scan chunk length
#define NCH     32          // SEQ / LC
#define DT      32          // d-channels per scan block
#define WX_KSPLIT 16
#define WX_KSEG   (D_IN / WX_KSPLIT)   // 128
#define OUT_KSPLIT 4
#define OUT_KSEG   (D_IN / OUT_KSPLIT) // 512

#define LOG2E   1.4426950408889634f

typedef __attribute__((ext_vector_type(8))) short bf16x8;
typedef __attribute__((ext_vector_type(4))) float f32x4;

__device__ __forceinline__ float fast_exp2(float x) { return __builtin_amdgcn_exp2f(x); }
__device__ __forceinline__ float fast_rcp(float x)  { return __builtin_amdgcn_rcpf(x); }

// async global->LDS, 16 bytes/lane; LDS dest = wave-uniform base + lane*16.
__device__ __forceinline__ void gload16(const ushort* g, ushort* l) {
    __builtin_amdgcn_global_load_lds(
        (const __attribute__((address_space(1))) void*)g,
        (__attribute__((address_space(3))) void*)l, 16, 0, 0);
}

// ---------------------------------------------------------------------------
// Compact conflict-free LDS layout for a 128x32 bf16 tile:
// 16B block (row r, k-octet ko) -> slot (r>>4)*64 + ko*16 + (r&15).
// A wave's MFMA fragment reads (f, lane(l4,l15)) hit slots
// b*64 + l4*16 + l15 -- 64 consecutive 16B slots => zero bank conflicts.
// Staging: thread t stages slots {t, t+256}; per-lane source (r,ko) inverted.
// ---------------------------------------------------------------------------
#define STAGE_T(SRC, BASE, LDK, KOFF, DSTB)                                    \
    _Pragma("unroll")                                                          \
    for (int q = 0; q < 2; ++q) {                                              \
        const int slot = q * 256 + t;                                          \
        const int rr   = ((slot >> 6) << 4) | (slot & 15);                     \
        const int ko   = (slot >> 4) & 3;                                      \
        gload16(&SRC[(size_t)((BASE) + rr) * (LDK) + (KOFF) + ko * 8],         \
                (DSTB) + (size_t)(q * 256 + wave * 64) * 8);                   \
    }

#define STAGE_ALL(BUF, KOFF, ABASE, BBASE, LDA_, LDB_)                         \
    STAGE_T(Ahi, ABASE, LDA_, KOFF, &lds[BUF][0][0])                           \
    STAGE_T(Alo, ABASE, LDA_, KOFF, &lds[BUF][1][0])                           \
    STAGE_T(Bhi, BBASE, LDB_, KOFF, &lds[BUF][2][0])                           \
    STAGE_T(Blo, BBASE, LDB_, KOFF, &lds[BUF][3][0])

#define COMPUTE32(BUF)                                                         \
    {                                                                          \
        bf16x8 ah[4], al[4], bh[4], bl[4];                                     \
        _Pragma("unroll")                                                      \
        for (int f = 0; f < 4; ++f) {                                          \
            const int ao = (((mw >> 4) + f) * 64 + l4 * 16 + l15) * 8;         \
            const int bo = (((nw >> 4) + f) * 64 + l4 * 16 + l15) * 8;         \
            ah[f] = *(const bf16x8*)&lds[BUF][0][ao];                          \
            al[f] = *(const bf16x8*)&lds[BUF][1][ao];                          \
            bh[f] = *(const bf16x8*)&lds[BUF][2][bo];                          \
            bl[f] = *(const bf16x8*)&lds[BUF][3][bo];                          \
        }                                                                      \
        _Pragma("unroll")                                                      \
        for (int i = 0; i < 4; ++i)                                            \
            _Pragma("unroll")                                                  \
            for (int j = 0; j < 4; ++j) {                                      \
                acc[i][j] = __builtin_amdgcn_mfma_f32_16x16x32_bf16(           \
                    ah[i], bh[j], acc[i][j], 0, 0, 0);                         \
                acc[i][j] = __builtin_amdgcn_mfma_f32_16x16x32_bf16(           \
                    ah[i], bl[j], acc[i][j], 0, 0, 0);                         \
                acc[i][j] = __builtin_amdgcn_mfma_f32_16x16x32_bf16(           \
                    al[i], bh[j], acc[i][j], 0, 0, 0);                         \
            }                                                                  \
    }

// 2-phase K-loop: stage t+1 -> compute t -> barrier (drain waits on loads that
// flew during compute).  One barrier per 32-K step.
#define KLOOP(KBEG, KEND, ABASE, BBASE, LDA_, LDB_)                            \
    STAGE_ALL(0, (KBEG), ABASE, BBASE, LDA_, LDB_)                             \
    __syncthreads();                                                           \
    {                                                                          \
        int cur = 0;                                                           \
        for (int k0 = (KBEG); k0 < (KEND); k0 += 32) {                         \
            const int nxt = cur ^ 1;                                           \
            if (k0 + 32 < (KEND)) {                                            \
                STAGE_ALL(nxt, k0 + 32, ABASE, BBASE, LDA_, LDB_)              \
            }                                                                  \
            COMPUTE32(cur)                                                     \
            __syncthreads();                                                   \
            cur = nxt;                                                         \
        }                                                                      \
    }

#define GEMM_PREAMBLE                                                          \
    const int t    = threadIdx.x;                                              \
    const int wave = t >> 6;                                                   \
    const int lane = t & 63;                                                   \
    const int mw   = (wave & 1) * 64;                                          \
    const int nw   = (wave >> 1) * 64;                                         \
    const int l15  = lane & 15;                                                \
    const int l4   = lane >> 4;                                                \
    f32x4 acc[4][4];                                                           \
    _Pragma("unroll")                                                          \
    for (int i = 0; i < 4; ++i)                                                \
        _Pragma("unroll")                                                      \
        for (int j = 0; j < 4; ++j)                                            \
            acc[i][j] = (f32x4){0.f, 0.f, 0.f, 0.f};

// v_add_f32 with DPP-moved operand: 16-lane butterfly without the DS pipe.
template <int CTRL>
__device__ __forceinline__ float dpp_add(float x) {
    int y = __builtin_amdgcn_update_dpp(0, __float_as_int(x), CTRL, 0xF, 0xF, true);
    return x + __int_as_float(y);
}

__device__ __forceinline__ ushort f2bf(float x) {
    unsigned u = __float_as_uint(x);
    u += 0x7FFFu + ((u >> 16) & 1u);      // RNE
    return (ushort)(u >> 16);
}
__device__ __forceinline__ float bf2f(ushort h) {
    return __uint_as_float(((unsigned)h) << 16);
}

// ---------------------------------------------------------------------------
// split fp32 -> bf16 hi/lo (elementwise). One float4 per thread.
// ---------------------------------------------------------------------------
__global__ __launch_bounds__(256) void split_bf16(
    const float* __restrict__ in, ushort* __restrict__ hi,
    ushort* __restrict__ lo)
{
    const int i = blockIdx.x * 256 + threadIdx.x;
    const float4 v = *(const float4*)&in[(size_t)i * 4];
    ushort4 h, l;
    h.x = f2bf(v.x); l.x = f2bf(v.x - bf2f(h.x));
    h.y = f2bf(v.y); l.y = f2bf(v.y - bf2f(h.y));
    h.z = f2bf(v.z); l.z = f2bf(v.z - bf2f(h.z));
    h.w = f2bf(v.w); l.w = f2bf(v.w - bf2f(h.w));
    *(ushort4*)&hi[(size_t)i * 4] = h;
    *(ushort4*)&lo[(size_t)i * 4] = l;
}

// ---------------------------------------------------------------------------
// split + transpose: in[R][C] fp32 -> hi/lo[C][R] bf16.
// ---------------------------------------------------------------------------
__global__ __launch_bounds__(256) void split_transpose(
    const float* __restrict__ in, ushort* __restrict__ hi,
    ushort* __restrict__ lo, int R, int C)
{
    __shared__ float tile[32][33];
    const int c0 = blockIdx.x * 32;
    const int r0 = blockIdx.y * 32;
    const int tc = threadIdx.x & 31;
    const int tr = threadIdx.x >> 5;
#pragma unroll
    for (int q = 0; q < 4; ++q)
        tile[tr + 8 * q][tc] = in[(size_t)(r0 + tr + 8 * q) * C + c0 + tc];
    __syncthreads();
#pragma unroll
    for (int q = 0; q < 4; ++q) {
        const float v = tile[tc][tr + 8 * q];
        const ushort h = f2bf(v);
        const ushort l = f2bf(v - bf2f(h));
        const size_t o = (size_t)(c0 + tr + 8 * q) * R + r0 + tc;
        hi[o] = h;
        lo[o] = l;
    }
}

// ---------------------------------------------------------------------------
// split + transpose with zero padding on the output-row axis.
// ---------------------------------------------------------------------------
__global__ __launch_bounds__(256) void split_transpose_pad(
    const float* __restrict__ in, ushort* __restrict__ hi,
    ushort* __restrict__ lo, int R, int Csrc)
{
    __shared__ float tile[32][33];
    const int c0 = blockIdx.x * 32;
    const int r0 = blockIdx.y * 32;
    const int tc = threadIdx.x & 31;
    const int tr = threadIdx.x >> 5;
#pragma unroll
    for (int q = 0; q < 4; ++q) {
        const int c = c0 + tc;
        tile[tr + 8 * q][tc] =
            (c < Csrc) ? in[(size_t)(r0 + tr + 8 * q) * Csrc + c] : 0.f;
    }
    __syncthreads();
#pragma unroll
    for (int q = 0; q < 4; ++q) {
        const float v = tile[tc][tr + 8 * q];
        const ushort h = f2bf(v);
        const ushort l = f2bf(v - bf2f(h));
        const size_t o = (size_t)(c0 + tr + 8 * q) * R + r0 + tc;
        hi[o] = h;
        lo[o] = l;
    }
}

// ---------------------------------------------------------------------------
// bf16x3-split MFMA GEMM (A row-major hi/lo, B transposed hi/lo).
// Double-buffered 2-phase K-loop, compact conflict-free LDS, BK=32.
// ---------------------------------------------------------------------------
__global__ __launch_bounds__(256) void gemm_mfma3(
    const ushort* __restrict__ Ahi, const ushort* __restrict__ Alo,
    const ushort* __restrict__ Bhi, const ushort* __restrict__ Blo,
    float* __restrict__ C0, float* __restrict__ C1, int nsplit,
    int M, int N, int K, int ldc0, int ldc1)
{
    __shared__ ushort lds[2][4][4096];   // [buf][Ahi,Alo,Bhi,Blo][128x32] 64KB
    const int m0 = blockIdx.y * 128;
    const int n0 = blockIdx.x * 128;
    GEMM_PREAMBLE

    KLOOP(0, K, m0, n0, K, K)

#pragma unroll
    for (int i = 0; i < 4; ++i) {
        const int rowg = m0 + mw + i * 16 + l4 * 4;
#pragma unroll
        for (int j = 0; j < 4; ++j) {
            const int colg = n0 + nw + j * 16 + l15;
            float* base;
            int cc, ldc;
            if (colg < nsplit) { base = C0; cc = colg;          ldc = ldc0; }
            else               { base = C1; cc = colg - nsplit; ldc = ldc1; }
#pragma unroll
            for (int v = 0; v < 4; ++v)
                base[(size_t)(rowg + v) * ldc + cc] = acc[i][j][v];
        }
    }
}

// ---------------------------------------------------------------------------
// split-K MFMA GEMM for x_dbl = u @ W_x (N padded 96->128).
// ---------------------------------------------------------------------------
__global__ __launch_bounds__(256) void gemm_wx_mfma(
    const ushort* __restrict__ Ahi, const ushort* __restrict__ Alo,
    const ushort* __restrict__ Bhi, const ushort* __restrict__ Blo,
    float* __restrict__ part)
{
    __shared__ ushort lds[2][4][4096];
    const int kb = blockIdx.x;
    const int m0 = blockIdx.y * 128;
    const int kbase = kb * WX_KSEG;
    GEMM_PREAMBLE

    KLOOP(kbase, kbase + WX_KSEG, m0, 0, D_IN, D_IN)

#pragma unroll
    for (int i = 0; i < 4; ++i) {
        const int rowg = m0 + mw + i * 16 + l4 * 4;
#pragma unroll
        for (int j = 0; j < 4; ++j) {
            const int colg = nw + j * 16 + l15;
#pragma unroll
            for (int v = 0; v < 4; ++v)
                part[((size_t)kb * SEQ + rowg + v) * XDBL_LD + colg] =
                    acc[i][j][v];
        }
    }
}

// Fixed-order reduction of the WX_KSPLIT partials -> xdbl [SEQ][XDBL_LD].
__global__ __launch_bounds__(256) void wx_reduce(
    const float* __restrict__ part, float* __restrict__ xdbl)
{
    const size_t i = (size_t)(blockIdx.x * 256 + threadIdx.x) * 4;
    float4 s = *(const float4*)&part[i];
#pragma unroll
    for (int kb = 1; kb < WX_KSPLIT; ++kb) {
        const float4 v = *(const float4*)&part[(size_t)kb * SEQ * XDBL_LD + i];
        s.x += v.x; s.y += v.y; s.z += v.z; s.w += v.w;
    }
    *(float4*)&xdbl[i] = s;
}

// ---------------------------------------------------------------------------
// split-K=4 MFMA GEMM for out = yg @ W_out.
// ---------------------------------------------------------------------------
__global__ __launch_bounds__(256) void gemm_out_mfma(
    const ushort* __restrict__ Ahi, const ushort* __restrict__ Alo,
    const ushort* __restrict__ Bhi, const ushort* __restrict__ Blo,
    float* __restrict__ p01, float* __restrict__ p23)
{
    __shared__ ushort lds[2][4][4096];
    const int n0 = blockIdx.x * 128;
    const int m0 = blockIdx.y * 128;
    const int kb = blockIdx.z;
    const int kbase = kb * OUT_KSEG;
    GEMM_PREAMBLE

    KLOOP(kbase, kbase + OUT_KSEG, m0, n0, D_IN, D_IN)

    float* base = (kb & 2) ? p23 : p01;
    base += (size_t)(kb & 1) * SEQ * D_MODEL;
#pragma unroll
    for (int i = 0; i < 4; ++i) {
        const int rowg = m0 + mw + i * 16 + l4 * 4;
#pragma unroll
        for (int j = 0; j < 4; ++j) {
            const int colg = n0 + nw + j * 16 + l15;
#pragma unroll
            for (int v = 0; v < 4; ++v)
                base[(size_t)(rowg + v) * D_MODEL + colg] = acc[i][j][v];
        }
    }
}

// Fixed-order reduce of the 4 output partials -> out [SEQ][D_MODEL].
__global__ __launch_bounds__(256) void out_reduce(
    const float* __restrict__ p01, const float* __restrict__ p23,
    float* __restrict__ out)
{
    const size_t i = (size_t)(blockIdx.x * 256 + threadIdx.x) * 4;
    const size_t MN = (size_t)SEQ * D_MODEL;
    const float4 a = *(const float4*)&p01[i];
    const float4 b = *(const float4*)&p01[i + MN];
    const float4 c = *(const float4*)&p23[i];
    const float4 d = *(const float4*)&p23[i + MN];
    float4 s;
    s.x = ((a.x + b.x) + c.x) + d.x;
    s.y = ((a.y + b.y) + c.y) + d.y;
    s.z = ((a.z + b.z) + c.z) + d.z;
    s.w = ((a.w + b.w) + c.w) + d.w;
    *(float4*)&out[i] = s;
}

// ---------------------------------------------------------------------------
// fp32 tiled GEMM (small delta GEMM, K=64)
// ---------------------------------------------------------------------------
__global__ __launch_bounds__(256) void gemm128(
    const float* __restrict__ A, const float* __restrict__ B,
    float* __restrict__ C, int M, int N, int K,
    int lda, int ldb, int ldc,
    const float* __restrict__ bias, int act)
{
    __shared__ float As[16][132];
    __shared__ float Bs[16][132];

    const int t   = threadIdx.x;
    const int bn0 = blockIdx.x * 128;
    const int bm0 = blockIdx.y * 128;
    const int tx  = t & 15;
    const int ty  = t >> 4;

    const int ar  = t >> 2;
    const int ak  = (t & 3) * 4;
    const int bk  = t >> 5;
    const int bn4 = (t & 31) * 4;

    float acc[8][8];
#pragma unroll
    for (int i = 0; i < 8; ++i)
#pragma unroll
        for (int j = 0; j < 8; ++j) acc[i][j] = 0.f;

    for (int k0 = 0; k0 < K; k0 += 16) {
        float4 a0 = *(const float4*)&A[(size_t)(bm0 + ar)      * lda + k0 + ak];
        float4 a1 = *(const float4*)&A[(size_t)(bm0 + ar + 64) * lda + k0 + ak];
        float4 b0 = *(const float4*)&B[(size_t)(k0 + bk)     * ldb + bn0 + bn4];
        float4 b1 = *(const float4*)&B[(size_t)(k0 + bk + 8) * ldb + bn0 + bn4];

        __syncthreads();
        As[ak + 0][ar] = a0.x; As[ak + 1][ar] = a0.y;
        As[ak + 2][ar] = a0.z; As[ak + 3][ar] = a0.w;
        As[ak + 0][ar + 64] = a1.x; As[ak + 1][ar + 64] = a1.y;
        As[ak + 2][ar + 64] = a1.z; As[ak + 3][ar + 64] = a1.w;
        *(float4*)&Bs[bk][bn4]     = b0;
        *(float4*)&Bs[bk + 8][bn4] = b1;
        __syncthreads();

#pragma unroll
        for (int kk = 0; kk < 16; ++kk) {
            float a[8], b[8];
            ((float4*)a)[0] = *(const float4*)&As[kk][ty * 8];
            ((float4*)a)[1] = *(const float4*)&As[kk][ty * 8 + 4];
            ((float4*)b)[0] = *(const float4*)&Bs[kk][tx * 8];
            ((float4*)b)[1] = *(const float4*)&Bs[kk][tx * 8 + 4];
#pragma unroll
            for (int i = 0; i < 8; ++i)
#pragma unroll
                for (int j = 0; j < 8; ++j)
                    acc[i][j] = fmaf(a[i], b[j], acc[i][j]);
        }
    }

    const int row = bm0 + ty * 8;
    const int col = bn0 + tx * 8;
#pragma unroll
    for (int i = 0; i < 8; ++i) {
        float vals[8];
#pragma unroll
        for (int j = 0; j < 8; ++j) {
            float v = acc[i][j];
            if (act == 1) {
                v += bias[col + j];
                v = (v > 20.f) ? v : log1pf(__expf(v));
            }
            vals[j] = v;
        }
        *(float4*)&C[(size_t)(row + i) * ldc + col]     = ((float4*)vals)[0];
        *(float4*)&C[(size_t)(row + i) * ldc + col + 4] = ((float4*)vals)[1];
    }
}

// ---------------------------------------------------------------------------
// Depthwise causal conv (K=3) + SiLU, fused with bf16 hi/lo split of u.
// ---------------------------------------------------------------------------
__global__ __launch_bounds__(256) void conv_silu_split(
    const float* __restrict__ xi, const float* __restrict__ cw,
    float* __restrict__ u, ushort* __restrict__ uhi, ushort* __restrict__ ulo)
{
    const int id = blockIdx.x * 256 + threadIdx.x;
    const int l = id >> 11;
    const int d = id & (D_IN - 1);
    const float w0 = cw[d * 3 + 0];
    const float w1 = cw[d * 3 + 1];
    const float w2 = cw[d * 3 + 2];
    const float x0  = xi[(size_t)l * D_IN + d];
    const float xm1 = (l >= 1) ? xi[(size_t)(l - 1) * D_IN + d] : 0.f;
    const float xm2 = (l >= 2) ? xi[(size_t)(l - 2) * D_IN + d] : 0.f;
    const float v = w0 * xm2 + w1 * xm1 + w2 * x0;
    const float s = fast_rcp(1.f + fast_exp2(-LOG2E * v));
    const float uu = v * s;
    u[id] = uu;
    const ushort h = f2bf(uu);
    uhi[id] = h;
    ulo[id] = f2bf(uu - bf2f(h));
}

// ---------------------------------------------------------------------------
// Per-chunk column sums of delta (double)
// ---------------------------------------------------------------------------
__global__ __launch_bounds__(256) void csum64(
    const float* __restrict__ delta, double* __restrict__ csum)
{
    const int d = blockIdx.x * 256 + threadIdx.x;
    const int c = blockIdx.y;
    double s = 0.0;
    for (int i = 0; i < LC; ++i)
        s += (double)delta[(size_t)(c * LC + i) * D_IN + d];
    csum[(size_t)c * D_IN + d] = s;
}

__global__ __launch_bounds__(256) void chunk_prefix(
    const double* __restrict__ csum, double* __restrict__ P0,
    double* __restrict__ Td)
{
    const int d = blockIdx.x * 256 + threadIdx.x;
    double P = 0.0;
    for (int c = 0; c < NCH; ++c) {
        P0[(size_t)c * D_IN + d] = P;
        P += csum[(size_t)c * D_IN + d];
    }
    Td[d] = P;
}

// ---------------------------------------------------------------------------
// sfx[l][d] = float(max(Td - P_inclusive(l), 0)); ALSO converts res -> rg =
// res*sigmoid(res) IN PLACE (res is regenerated by gemm1 every call).
// ---------------------------------------------------------------------------
__global__ __launch_bounds__(256) void sfx_precompute(
    const float* __restrict__ delta, const double* __restrict__ P0,
    const double* __restrict__ Td, float* __restrict__ sfx,
    float* __restrict__ res)
{
    const int d = blockIdx.x * 256 + threadIdx.x;
    const int c = blockIdx.y;
    double P = P0[(size_t)c * D_IN + d];
    const double T = Td[d];
    for (int i = 0; i < LC; ++i) {
        const size_t row = (size_t)(c * LC + i) * D_IN + d;
        P += (double)delta[row];
        sfx[row] = (float)fmax(T - P, 0.0);
        const float r = res[row];
        res[row] = r * fast_rcp(1.f + fast_exp2(-LOG2E * r));
    }
}

// ---------------------------------------------------------------------------
// Pass A (cumsum form): Wc[c,d,n] = sum_j du[j]*B[j,n]*exp2(An2*sfx[j]).
// ---------------------------------------------------------------------------
__global__ __launch_bounds__(512) void scan_partA(
    const float* __restrict__ delta, const float* __restrict__ u,
    const float* __restrict__ sfxbuf, const float* __restrict__ xdbl,
    const float* __restrict__ Alog, float* __restrict__ Wc)
{
    __shared__ float2 spA[LC][DT];     // (delta*u, sfx)  16 KB
    __shared__ float  sBA[LC][16];     // B                4 KB

    const int t  = threadIdx.x;
    const int c  = blockIdx.x;
    const int d0 = blockIdx.y * DT;

    {
        const int r = t >> 3, c4 = (t & 7) * 4;
        const size_t row = (size_t)(c * LC + r) * D_IN + d0 + c4;
        const float4 dv4 = *(const float4*)&delta[row];
        const float4 uv4 = *(const float4*)&u[row];
        const float4 sx4 = *(const float4*)&sfxbuf[row];
        spA[r][c4 + 0] = make_float2(dv4.x * uv4.x, sx4.x);
        spA[r][c4 + 1] = make_float2(dv4.y * uv4.y, sx4.y);
        spA[r][c4 + 2] = make_float2(dv4.z * uv4.z, sx4.z);
        spA[r][c4 + 3] = make_float2(dv4.w * uv4.w, sx4.w);
    }
    if (t < 256) {
        const int r = t >> 2, c4 = (t & 3) * 4;
        *(float4*)&sBA[r][c4] =
            *(const float4*)&xdbl[(size_t)(c * LC + r) * XDBL_LD + DT_RANK + c4];
    }
    __syncthreads();

    const int n  = t & 15;
    const int dq = t >> 4;
    const int d  = d0 + dq;
    const float An2 = -expf(Alog[d * N_STATE + n]) * LOG2E;

    float W = 0.f;
#pragma unroll
    for (int i = 0; i < LC; ++i) {
        const float2 p = spA[i][dq];
        W = fmaf(p.x * sBA[i][n], fast_exp2(An2 * p.y), W);
    }
    Wc[((size_t)c * D_IN + d) * N_STATE + n] = W;
}

// ---------------------------------------------------------------------------
// Pass B: exclusive prefix over chunks (plain adds; cumsum form).
// ---------------------------------------------------------------------------
__global__ __launch_bounds__(256) void scan_combine(float* __restrict__ Wc)
{
    const int id = blockIdx.x * 256 + threadIdx.x;   // (d,n)
    float W = 0.f;
    for (int c = 0; c < NCH; ++c) {
        const size_t idx = (size_t)c * (D_IN * N_STATE) + id;
        const float w = Wc[idx];
        Wc[idx] = W;
        W += w;
    }
}

// ---------------------------------------------------------------------------
// Pass C (cumsum form): W += du*B*E; xs = W/(E+1e-12); y = sum_n xs*C; *rg.
// ---------------------------------------------------------------------------
__global__ __launch_bounds__(512) void scan_partC(
    const float* __restrict__ delta, const float* __restrict__ u,
    const float* __restrict__ xdbl, const float* __restrict__ W0buf,
    const float* __restrict__ sfxbuf, const float* __restrict__ Alog,
    const float* __restrict__ Dvec, const float* __restrict__ rgbuf,
    float* __restrict__ yg)
{
    __shared__ float4 spack[LC][DT];   // 32 KB
    __shared__ float2 sbc[LC][16];     //  8 KB

    const int t  = threadIdx.x;
    const int c  = blockIdx.x;
    const int d0 = blockIdx.y * DT;

    {
        const int r = t >> 3, c4 = (t & 7) * 4;
        const size_t row = (size_t)(c * LC + r) * D_IN + d0 + c4;
        const float4 dv4 = *(const float4*)&delta[row];
        const float4 uv4 = *(const float4*)&u[row];
        const float4 sx4 = *(const float4*)&sfxbuf[row];
        const float4 rg4 = *(const float4*)&rgbuf[row];
        spack[r][c4 + 0] = make_float4(dv4.x * uv4.x, sx4.x, uv4.x, rg4.x);
        spack[r][c4 + 1] = make_float4(dv4.y * uv4.y, sx4.y, uv4.y, rg4.y);
        spack[r][c4 + 2] = make_float4(dv4.z * uv4.z, sx4.z, uv4.z, rg4.z);
        spack[r][c4 + 3] = make_float4(dv4.w * uv4.w, sx4.w, uv4.w, rg4.w);
    }
    if (t < 256) {
        const int r = t >> 2, n4 = (t & 3) * 4;
        const float4 b4 = *(const float4*)&xdbl[(size_t)(c * LC + r) * XDBL_LD + DT_RANK + n4];
        const float4 c4v = *(const float4*)&xdbl[(size_t)(c * LC + r) * XDBL_LD + DT_RANK + 16 + n4];
        sbc[r][n4 + 0] = make_float2(b4.x, c4v.x);
        sbc[r][n4 + 1] = make_float2(b4.y, c4v.y);
        sbc[r][n4 + 2] = make_float2(b4.z, c4v.z);
        sbc[r][n4 + 3] = make_float2(b4.w, c4v.w);
    }
    __syncthreads();

    const int n  = t & 15;
    const int dq = t >> 4;
    const int d  = d0 + dq;
    const float An2 = -expf(Alog[d * N_STATE + n]) * LOG2E;
    const float Dd = Dvec[d];

    float W = W0buf[((size_t)c * D_IN + d) * N_STATE + n];

#pragma unroll
    for (int i = 0; i < LC; ++i) {
        const float4 p = spack[i][dq];
        const float2 bc = sbc[i][n];
        const float E = fast_exp2(An2 * p.y);
        W = fmaf(p.x * bc.x, E, W);
        const float xs = W * fast_rcp(E + 1e-12f);
        float contrib = xs * bc.y;
        contrib = dpp_add<0xB1>(contrib);    // quad_perm 1,0,3,2  (xor 1)
        contrib = dpp_add<0x4E>(contrib);    // quad_perm 2,3,0,1  (xor 2)
        contrib = dpp_add<0x128>(contrib);   // row_ror:8
        contrib = dpp_add<0x124>(contrib);   // row_ror:4
        if (n == 0) {
            yg[(size_t)(c * LC + i) * D_IN + d] =
                fmaf(p.z, Dd, contrib) * p.w;
        }
    }
}

// ---------------------------------------------------------------------------
// Launch.  Workspace (74.5 MB peak, time-multiplexed; ws proven >= 84.9 MB):
//   [ 0    ,16.78M): xi -> wxp -> sfx -> yg_hi/yg_lo
//   [16.78 ,33.55 ): res (becomes rg in-place) -> out partials p01
//   [33.55 ,50.33 ): x_hi/x_lo -> u (f32) -> wo_hi/wo_lo
//   [50.33 ,51.38 ): xdbl [2048][128] f32
//   [51.38 ,68.16 ): wi_hi/wi_lo -> u_hi/u_lo -> delta/yg -> p23
//   [68.16 ,73.42 ): Wc/W0, csum, P0, Td
//   [73.42 ,74.47 ): wx_hi/wx_lo
// ---------------------------------------------------------------------------
extern "C" void kernel_launch(void* const* d_in, const int* in_sizes, int n_in,
                              void* d_out, int out_size, void* d_ws, size_t ws_size,
                              hipStream_t stream)
{
    const float* x      = (const float*)d_in[0];
    const float* W_in   = (const float*)d_in[1];
    const float* conv_w = (const float*)d_in[2];
    const float* W_x    = (const float*)d_in[3];
    const float* W_del  = (const float*)d_in[4];
    const float* b_del  = (const float*)d_in[5];
    const float* A_log  = (const float*)d_in[6];
    const float* Dv     = (const float*)d_in[7];
    const float* W_out  = (const float*)d_in[8];
    float* out = (float*)d_out;

    char* ws = (char*)d_ws;
    float*  xi    = (float*)(ws + 0);
    float*  wxp   = (float*)(ws + 0);
    float*  sfx   = (float*)(ws + 0);
    ushort* yg_hi = (ushort*)(ws + 0);
    ushort* yg_lo = (ushort*)(ws + 8388608);
    float*  res   = (float*)(ws + 16777216);   // becomes rg in sfx_precompute
    float*  p01   = (float*)(ws + 16777216);
    ushort* x_hi  = (ushort*)(ws + 33554432);
    ushort* x_lo  = (ushort*)(ws + 37748736);
    float*  u     = (float*)(ws + 33554432);
    ushort* wo_hi = (ushort*)(ws + 33554432);
    ushort* wo_lo = (ushort*)(ws + 37748736);
    float*  xdbl  = (float*)(ws + 50331648);
    ushort* wi_hi = (ushort*)(ws + 51380224);
    ushort* wi_lo = (ushort*)(ws + 59768832);
    ushort* u_hi  = (ushort*)(ws + 51380224);
    ushort* u_lo  = (ushort*)(ws + 59768832);
    float*  delta = (float*)(ws + 51380224);
    float*  p23   = (float*)(ws + 51380224);
    float*  Wc    = (float*)(ws + 68157440);   // 4.19 MB
    double* csum  = (double*)(ws + 72351744);
    double* P0    = (double*)(ws + 72876032);
    double* Td    = (double*)(ws + 73400320);
    ushort* wx_hi = (ushort*)(ws + 73416704);
    ushort* wx_lo = (ushort*)(ws + 73940992);
    float*  yg    = delta;

    // 1) W_in^T split
    split_transpose<<<dim3(4096 / 32, 1024 / 32), 256, 0, stream>>>(
        W_in, wi_hi, wi_lo, 1024, 4096);

    // 2) x split
    split_bf16<<<(SEQ * D_MODEL / 4) / 256, 256, 0, stream>>>(x, x_hi, x_lo);

    // 3) [xi | res] = x @ W_in
    gemm_mfma3<<<dim3(4096 / 128, 2048 / 128), 256, 0, stream>>>(
        x_hi, x_lo, wi_hi, wi_lo, xi, res, D_IN,
        SEQ, 2 * D_IN, D_MODEL, D_IN, D_IN);

    // 4) u = silu(conv(xi)) + u hi/lo split (fused)
    conv_silu_split<<<(SEQ * D_IN) / 256, 256, 0, stream>>>(
        xi, conv_w, u, u_hi, u_lo);

    // 5) W_x^T padded split
    split_transpose_pad<<<dim3(XDBL_LD / 32, D_IN / 32), 256, 0, stream>>>(
        W_x, wx_hi, wx_lo, D_IN, XDBL_W);

    // 6) x_dbl = u @ W_x  (split-K MFMA, fixed-order reduce)
    gemm_wx_mfma<<<dim3(WX_KSPLIT, SEQ / 128), 256, 0, stream>>>(
        u_hi, u_lo, wx_hi, wx_lo, wxp);
    wx_reduce<<<(SEQ * XDBL_LD / 4) / 256, 256, 0, stream>>>(wxp, xdbl);

    // 7) delta = softplus(delta_lr @ W_delta + b_delta)
    gemm128<<<dim3(2048 / 128, 2048 / 128), 256, 0, stream>>>(
        xdbl, W_del, delta, SEQ, D_IN, DT_RANK, XDBL_LD, D_IN, D_IN,
        b_del, 1);

    // 8) chunk sums + prefix + suffix/rg precompute (double, deterministic)
    csum64<<<dim3(D_IN / 256, NCH), 256, 0, stream>>>(delta, csum);
    chunk_prefix<<<D_IN / 256, 256, 0, stream>>>(csum, P0, Td);
    sfx_precompute<<<dim3(D_IN / 256, NCH), 256, 0, stream>>>(
        delta, P0, Td, sfx, res);

    // 9) chunk-parallel scan (cumsum form)
    scan_partA<<<dim3(NCH, D_IN / DT), 512, 0, stream>>>(
        delta, u, sfx, xdbl, A_log, Wc);
    scan_combine<<<(D_IN * N_STATE) / 256, 256, 0, stream>>>(Wc);
    scan_partC<<<dim3(NCH, D_IN / DT), 512, 0, stream>>>(
        delta, u, xdbl, Wc, sfx, A_log, Dv, res, yg);

    // 10) yg split (sfx dead; region reused)
    split_bf16<<<(SEQ * D_IN / 4) / 256, 256, 0, stream>>>(yg, yg_hi, yg_lo);

    // 11) W_out^T split (u dead; region reused)
    split_transpose<<<dim3(1024 / 32, 2048 / 32), 256, 0, stream>>>(
        W_out, wo_hi, wo_lo, 2048, 1024);

    // 12) out = yg @ W_out  (split-K=4; partials in dead regions)
    gemm_out_mfma<<<dim3(D_MODEL / 128, SEQ / 128, OUT_KSPLIT), 256, 0, stream>>>(
        yg_hi, yg_lo, wo_hi, wo_lo, p01, p23);
    out_reduce<<<(SEQ * D_MODEL / 4) / 256, 256, 0, stream>>>(p01, p23, out);
}

// Round 12
// 256.298 us; speedup vs baseline: 1.1483x; 1.1483x over previous
//
#include <hip/hip_runtime.h>
#include <hip/hip_bf16.h>
#include <math.h>

// ---------------------------------------------------------------------------
// Shapes (compile-time constants for this problem)
// ---------------------------------------------------------------------------
#define SEQ     2048
#define D_MODEL 1024
#define D_IN    2048
#define N_STATE 16
#define DT_RANK 64
#define XDBL_W  96          // DT_RANK + 2*N_STATE
#define XDBL_LD 128         // padded leading dim of x_dbl
#define LC      64          // scan chunk length
#define NCH     32          // SEQ / LC
#define DT      32          // d-channels per scan block
#define WX_KSPLIT 16
#define WX_KSEG   (D_IN / WX_KSPLIT)   // 128
#define OUT_KSPLIT 4
#define OUT_KSEG   (D_IN / OUT_KSPLIT) // 512

#define LOG2E   1.4426950408889634f

typedef __attribute__((ext_vector_type(8))) short bf16x8;
typedef __attribute__((ext_vector_type(4))) float f32x4;

__device__ __forceinline__ float fast_exp2(float x) { return __builtin_amdgcn_exp2f(x); }
__device__ __forceinline__ float fast_rcp(float x)  { return __builtin_amdgcn_rcpf(x); }

// async global->LDS, 16 bytes/lane; LDS dest = wave-uniform base + lane*16.
__device__ __forceinline__ void gload16(const ushort* g, ushort* l) {
    __builtin_amdgcn_global_load_lds(
        (const __attribute__((address_space(1))) void*)g,
        (__attribute__((address_space(3))) void*)l, 16, 0, 0);
}

// Pre-swizzled-source staging: LDS linear (slot idx = q*256 + wave*64 + lane),
// each lane fetches global col-block (lane&7)^(lane>>3) so LDS holds the
// XOR-swizzled layout ( [r][ (kc^(r&7))*8 ] ) the MFMA ds_read_b128 expects.
#define GL_DEFS                                                                \
    const int lane8 = lane >> 3;                                               \
    const int scol  = (lane & 7) ^ lane8;                                      \
    const int wq    = wave * 8;

#define STAGE_GL(SRC, DST, BASE, LDK, KOFF)                                    \
    _Pragma("unroll")                                                          \
    for (int q = 0; q < 4; ++q) {                                              \
        const int rr = q * 32 + wq + lane8;                                    \
        gload16(&SRC[(size_t)((BASE) + rr) * (LDK) + (KOFF) + scol * 8],       \
                ((ushort*)DST) + (q * 256 + wave * 64) * 8);                   \
    }

// v_add_f32 with DPP-moved operand: 16-lane butterfly without the DS pipe.
template <int CTRL>
__device__ __forceinline__ float dpp_add(float x) {
    int y = __builtin_amdgcn_update_dpp(0, __float_as_int(x), CTRL, 0xF, 0xF, true);
    return x + __int_as_float(y);
}

__device__ __forceinline__ ushort f2bf(float x) {
    unsigned u = __float_as_uint(x);
    u += 0x7FFFu + ((u >> 16) & 1u);      // RNE
    return (ushort)(u >> 16);
}
__device__ __forceinline__ float bf2f(ushort h) {
    return __uint_as_float(((unsigned)h) << 16);
}

// ---------------------------------------------------------------------------
// split fp32 -> bf16 hi/lo (elementwise). One float4 per thread.
// ---------------------------------------------------------------------------
__global__ __launch_bounds__(256) void split_bf16(
    const float* __restrict__ in, ushort* __restrict__ hi,
    ushort* __restrict__ lo)
{
    const int i = blockIdx.x * 256 + threadIdx.x;
    const float4 v = *(const float4*)&in[(size_t)i * 4];
    ushort4 h, l;
    h.x = f2bf(v.x); l.x = f2bf(v.x - bf2f(h.x));
    h.y = f2bf(v.y); l.y = f2bf(v.y - bf2f(h.y));
    h.z = f2bf(v.z); l.z = f2bf(v.z - bf2f(h.z));
    h.w = f2bf(v.w); l.w = f2bf(v.w - bf2f(h.w));
    *(ushort4*)&hi[(size_t)i * 4] = h;
    *(ushort4*)&lo[(size_t)i * 4] = l;
}

// ---------------------------------------------------------------------------
// split + transpose: in[R][C] fp32 -> hi/lo[C][R] bf16.
// ---------------------------------------------------------------------------
__global__ __launch_bounds__(256) void split_transpose(
    const float* __restrict__ in, ushort* __restrict__ hi,
    ushort* __restrict__ lo, int R, int C)
{
    __shared__ float tile[32][33];
    const int c0 = blockIdx.x * 32;
    const int r0 = blockIdx.y * 32;
    const int tc = threadIdx.x & 31;
    const int tr = threadIdx.x >> 5;
#pragma unroll
    for (int q = 0; q < 4; ++q)
        tile[tr + 8 * q][tc] = in[(size_t)(r0 + tr + 8 * q) * C + c0 + tc];
    __syncthreads();
#pragma unroll
    for (int q = 0; q < 4; ++q) {
        const float v = tile[tc][tr + 8 * q];
        const ushort h = f2bf(v);
        const ushort l = f2bf(v - bf2f(h));
        const size_t o = (size_t)(c0 + tr + 8 * q) * R + r0 + tc;
        hi[o] = h;
        lo[o] = l;
    }
}

// ---------------------------------------------------------------------------
// split + transpose with zero padding on the output-row axis.
// ---------------------------------------------------------------------------
__global__ __launch_bounds__(256) void split_transpose_pad(
    const float* __restrict__ in, ushort* __restrict__ hi,
    ushort* __restrict__ lo, int R, int Csrc)
{
    __shared__ float tile[32][33];
    const int c0 = blockIdx.x * 32;
    const int r0 = blockIdx.y * 32;
    const int tc = threadIdx.x & 31;
    const int tr = threadIdx.x >> 5;
#pragma unroll
    for (int q = 0; q < 4; ++q) {
        const int c = c0 + tc;
        tile[tr + 8 * q][tc] =
            (c < Csrc) ? in[(size_t)(r0 + tr + 8 * q) * Csrc + c] : 0.f;
    }
    __syncthreads();
#pragma unroll
    for (int q = 0; q < 4; ++q) {
        const float v = tile[tc][tr + 8 * q];
        const ushort h = f2bf(v);
        const ushort l = f2bf(v - bf2f(h));
        const size_t o = (size_t)(c0 + tr + 8 * q) * R + r0 + tc;
        hi[o] = h;
        lo[o] = l;
    }
}

// ---------------------------------------------------------------------------
// bf16x3-split MFMA GEMM (A row-major hi/lo, B transposed hi/lo).
// acc += Ahi*Bhi + Ahi*Blo + Alo*Bhi.  Tile 128x128, K-step 64, 4 waves.
// Staging via global_load_lds with pre-swizzled source (round-10 proven).
// C1 epilogue applies SiLU gate: stores v*sigmoid(v) (used for res -> rg).
// ---------------------------------------------------------------------------
__global__ __launch_bounds__(256) void gemm_mfma3(
    const ushort* __restrict__ Ahi, const ushort* __restrict__ Alo,
    const ushort* __restrict__ Bhi, const ushort* __restrict__ Blo,
    float* __restrict__ C0, float* __restrict__ C1, int nsplit,
    int M, int N, int K, int ldc0, int ldc1)
{
    __shared__ ushort lA[2][128][64];
    __shared__ ushort lB[2][128][64];

    const int t    = threadIdx.x;
    const int m0   = blockIdx.y * 128;
    const int n0   = blockIdx.x * 128;
    const int wave = t >> 6;
    const int lane = t & 63;
    const int mw   = (wave & 1) * 64;
    const int nw   = (wave >> 1) * 64;
    const int l15  = lane & 15;
    const int l4   = lane >> 4;
    const int sw   = l15 & 7;
    GL_DEFS

    f32x4 acc[4][4];
#pragma unroll
    for (int i = 0; i < 4; ++i)
#pragma unroll
        for (int j = 0; j < 4; ++j)
            acc[i][j] = (f32x4){0.f, 0.f, 0.f, 0.f};

    for (int k0 = 0; k0 < K; k0 += 64) {
        __syncthreads();
        STAGE_GL(Ahi, lA[0], m0, K, k0)
        STAGE_GL(Alo, lA[1], m0, K, k0)
        STAGE_GL(Bhi, lB[0], n0, K, k0)
        STAGE_GL(Blo, lB[1], n0, K, k0)
        __syncthreads();

#pragma unroll
        for (int ks = 0; ks < 2; ++ks) {
            const int slot = (((ks << 2) | l4) ^ sw) * 8;
            bf16x8 ah[4], al[4], bh[4], bl[4];
#pragma unroll
            for (int f = 0; f < 4; ++f) {
                const int ar = mw + f * 16 + l15;
                const int br = nw + f * 16 + l15;
                ah[f] = *(const bf16x8*)&lA[0][ar][slot];
                al[f] = *(const bf16x8*)&lA[1][ar][slot];
                bh[f] = *(const bf16x8*)&lB[0][br][slot];
                bl[f] = *(const bf16x8*)&lB[1][br][slot];
            }
#pragma unroll
            for (int i = 0; i < 4; ++i)
#pragma unroll
                for (int j = 0; j < 4; ++j) {
                    acc[i][j] = __builtin_amdgcn_mfma_f32_16x16x32_bf16(
                        ah[i], bh[j], acc[i][j], 0, 0, 0);
                    acc[i][j] = __builtin_amdgcn_mfma_f32_16x16x32_bf16(
                        ah[i], bl[j], acc[i][j], 0, 0, 0);
                    acc[i][j] = __builtin_amdgcn_mfma_f32_16x16x32_bf16(
                        al[i], bh[j], acc[i][j], 0, 0, 0);
                }
        }
    }

#pragma unroll
    for (int i = 0; i < 4; ++i) {
        const int rowg = m0 + mw + i * 16 + l4 * 4;
#pragma unroll
        for (int j = 0; j < 4; ++j) {
            const int colg = n0 + nw + j * 16 + l15;
            if (colg < nsplit) {
#pragma unroll
                for (int v = 0; v < 4; ++v)
                    C0[(size_t)(rowg + v) * ldc0 + colg] = acc[i][j][v];
            } else {
                const int cc = colg - nsplit;
#pragma unroll
                for (int v = 0; v < 4; ++v) {
                    const float r = acc[i][j][v];
                    C1[(size_t)(rowg + v) * ldc1 + cc] =
                        r * fast_rcp(1.f + fast_exp2(-LOG2E * r));
                }
            }
        }
    }
}

// ---------------------------------------------------------------------------
// split-K MFMA GEMM for x_dbl = u @ W_x (N padded 96->128).
// ---------------------------------------------------------------------------
__global__ __launch_bounds__(256) void gemm_wx_mfma(
    const ushort* __restrict__ Ahi, const ushort* __restrict__ Alo,
    const ushort* __restrict__ Bhi, const ushort* __restrict__ Blo,
    float* __restrict__ part)
{
    __shared__ ushort lA[2][128][64];
    __shared__ ushort lB[2][128][64];

    const int t    = threadIdx.x;
    const int kb   = blockIdx.x;
    const int m0   = blockIdx.y * 128;
    const int wave = t >> 6;
    const int lane = t & 63;
    const int mw   = (wave & 1) * 64;
    const int nw   = (wave >> 1) * 64;
    const int l15  = lane & 15;
    const int l4   = lane >> 4;
    const int sw   = l15 & 7;
    const int kbase = kb * WX_KSEG;
    GL_DEFS

    f32x4 acc[4][4];
#pragma unroll
    for (int i = 0; i < 4; ++i)
#pragma unroll
        for (int j = 0; j < 4; ++j)
            acc[i][j] = (f32x4){0.f, 0.f, 0.f, 0.f};

    for (int k0 = 0; k0 < WX_KSEG; k0 += 64) {
        __syncthreads();
        STAGE_GL(Ahi, lA[0], m0, D_IN, kbase + k0)
        STAGE_GL(Alo, lA[1], m0, D_IN, kbase + k0)
        STAGE_GL(Bhi, lB[0], 0,  D_IN, kbase + k0)
        STAGE_GL(Blo, lB[1], 0,  D_IN, kbase + k0)
        __syncthreads();

#pragma unroll
        for (int ks = 0; ks < 2; ++ks) {
            const int slot = (((ks << 2) | l4) ^ sw) * 8;
            bf16x8 ah[4], al[4], bh[4], bl[4];
#pragma unroll
            for (int f = 0; f < 4; ++f) {
                const int ar = mw + f * 16 + l15;
                const int br = nw + f * 16 + l15;
                ah[f] = *(const bf16x8*)&lA[0][ar][slot];
                al[f] = *(const bf16x8*)&lA[1][ar][slot];
                bh[f] = *(const bf16x8*)&lB[0][br][slot];
                bl[f] = *(const bf16x8*)&lB[1][br][slot];
            }
#pragma unroll
            for (int i = 0; i < 4; ++i)
#pragma unroll
                for (int j = 0; j < 4; ++j) {
                    acc[i][j] = __builtin_amdgcn_mfma_f32_16x16x32_bf16(
                        ah[i], bh[j], acc[i][j], 0, 0, 0);
                    acc[i][j] = __builtin_amdgcn_mfma_f32_16x16x32_bf16(
                        ah[i], bl[j], acc[i][j], 0, 0, 0);
                    acc[i][j] = __builtin_amdgcn_mfma_f32_16x16x32_bf16(
                        al[i], bh[j], acc[i][j], 0, 0, 0);
                }
        }
    }

#pragma unroll
    for (int i = 0; i < 4; ++i) {
        const int rowg = m0 + mw + i * 16 + l4 * 4;
#pragma unroll
        for (int j = 0; j < 4; ++j) {
            const int colg = nw + j * 16 + l15;
#pragma unroll
            for (int v = 0; v < 4; ++v)
                part[((size_t)kb * SEQ + rowg + v) * XDBL_LD + colg] =
                    acc[i][j][v];
        }
    }
}

// Fixed-order reduction of the WX_KSPLIT partials -> xdbl [SEQ][XDBL_LD].
__global__ __launch_bounds__(256) void wx_reduce(
    const float* __restrict__ part, float* __restrict__ xdbl)
{
    const size_t i = (size_t)(blockIdx.x * 256 + threadIdx.x) * 4;
    float4 s = *(const float4*)&part[i];
#pragma unroll
    for (int kb = 1; kb < WX_KSPLIT; ++kb) {
        const float4 v = *(const float4*)&part[(size_t)kb * SEQ * XDBL_LD + i];
        s.x += v.x; s.y += v.y; s.z += v.z; s.w += v.w;
    }
    *(float4*)&xdbl[i] = s;
}

// ---------------------------------------------------------------------------
// split-K=4 MFMA GEMM for out = yg @ W_out.
// ---------------------------------------------------------------------------
__global__ __launch_bounds__(256) void gemm_out_mfma(
    const ushort* __restrict__ Ahi, const ushort* __restrict__ Alo,
    const ushort* __restrict__ Bhi, const ushort* __restrict__ Blo,
    float* __restrict__ p01, float* __restrict__ p23)
{
    __shared__ ushort lA[2][128][64];
    __shared__ ushort lB[2][128][64];

    const int t    = threadIdx.x;
    const int n0   = blockIdx.x * 128;
    const int m0   = blockIdx.y * 128;
    const int kb   = blockIdx.z;
    const int wave = t >> 6;
    const int lane = t & 63;
    const int mw   = (wave & 1) * 64;
    const int nw   = (wave >> 1) * 64;
    const int l15  = lane & 15;
    const int l4   = lane >> 4;
    const int sw   = l15 & 7;
    const int kbase = kb * OUT_KSEG;
    GL_DEFS

    f32x4 acc[4][4];
#pragma unroll
    for (int i = 0; i < 4; ++i)
#pragma unroll
        for (int j = 0; j < 4; ++j)
            acc[i][j] = (f32x4){0.f, 0.f, 0.f, 0.f};

    for (int k0 = 0; k0 < OUT_KSEG; k0 += 64) {
        __syncthreads();
        STAGE_GL(Ahi, lA[0], m0, D_IN, kbase + k0)
        STAGE_GL(Alo, lA[1], m0, D_IN, kbase + k0)
        STAGE_GL(Bhi, lB[0], n0, D_IN, kbase + k0)
        STAGE_GL(Blo, lB[1], n0, D_IN, kbase + k0)
        __syncthreads();

#pragma unroll
        for (int ks = 0; ks < 2; ++ks) {
            const int slot = (((ks << 2) | l4) ^ sw) * 8;
            bf16x8 ah[4], al[4], bh[4], bl[4];
#pragma unroll
            for (int f = 0; f < 4; ++f) {
                const int ar = mw + f * 16 + l15;
                const int br = nw + f * 16 + l15;
                ah[f] = *(const bf16x8*)&lA[0][ar][slot];
                al[f] = *(const bf16x8*)&lA[1][ar][slot];
                bh[f] = *(const bf16x8*)&lB[0][br][slot];
                bl[f] = *(const bf16x8*)&lB[1][br][slot];
            }
#pragma unroll
            for (int i = 0; i < 4; ++i)
#pragma unroll
                for (int j = 0; j < 4; ++j) {
                    acc[i][j] = __builtin_amdgcn_mfma_f32_16x16x32_bf16(
                        ah[i], bh[j], acc[i][j], 0, 0, 0);
                    acc[i][j] = __builtin_amdgcn_mfma_f32_16x16x32_bf16(
                        ah[i], bl[j], acc[i][j], 0, 0, 0);
                    acc[i][j] = __builtin_amdgcn_mfma_f32_16x16x32_bf16(
                        al[i], bh[j], acc[i][j], 0, 0, 0);
                }
        }
    }

    float* base = (kb & 2) ? p23 : p01;
    base += (size_t)(kb & 1) * SEQ * D_MODEL;
#pragma unroll
    for (int i = 0; i < 4; ++i) {
        const int rowg = m0 + mw + i * 16 + l4 * 4;
#pragma unroll
        for (int j = 0; j < 4; ++j) {
            const int colg = n0 + nw + j * 16 + l15;
#pragma unroll
            for (int v = 0; v < 4; ++v)
                base[(size_t)(rowg + v) * D_MODEL + colg] = acc[i][j][v];
        }
    }
}

// Fixed-order reduce of the 4 output partials -> out [SEQ][D_MODEL].
__global__ __launch_bounds__(256) void out_reduce(
    const float* __restrict__ p01, const float* __restrict__ p23,
    float* __restrict__ out)
{
    const size_t i = (size_t)(blockIdx.x * 256 + threadIdx.x) * 4;
    const size_t MN = (size_t)SEQ * D_MODEL;
    const float4 a = *(const float4*)&p01[i];
    const float4 b = *(const float4*)&p01[i + MN];
    const float4 c = *(const float4*)&p23[i];
    const float4 d = *(const float4*)&p23[i + MN];
    float4 s;
    s.x = ((a.x + b.x) + c.x) + d.x;
    s.y = ((a.y + b.y) + c.y) + d.y;
    s.z = ((a.z + b.z) + c.z) + d.z;
    s.w = ((a.w + b.w) + c.w) + d.w;
    *(float4*)&out[i] = s;
}

// ---------------------------------------------------------------------------
// fp32 tiled GEMM (small delta GEMM, K=64)
// ---------------------------------------------------------------------------
__global__ __launch_bounds__(256) void gemm128(
    const float* __restrict__ A, const float* __restrict__ B,
    float* __restrict__ C, int M, int N, int K,
    int lda, int ldb, int ldc,
    const float* __restrict__ bias, int act)
{
    __shared__ float As[16][132];
    __shared__ float Bs[16][132];

    const int t   = threadIdx.x;
    const int bn0 = blockIdx.x * 128;
    const int bm0 = blockIdx.y * 128;
    const int tx  = t & 15;
    const int ty  = t >> 4;

    const int ar  = t >> 2;
    const int ak  = (t & 3) * 4;
    const int bk  = t >> 5;
    const int bn4 = (t & 31) * 4;

    float acc[8][8];
#pragma unroll
    for (int i = 0; i < 8; ++i)
#pragma unroll
        for (int j = 0; j < 8; ++j) acc[i][j] = 0.f;

    for (int k0 = 0; k0 < K; k0 += 16) {
        float4 a0 = *(const float4*)&A[(size_t)(bm0 + ar)      * lda + k0 + ak];
        float4 a1 = *(const float4*)&A[(size_t)(bm0 + ar + 64) * lda + k0 + ak];
        float4 b0 = *(const float4*)&B[(size_t)(k0 + bk)     * ldb + bn0 + bn4];
        float4 b1 = *(const float4*)&B[(size_t)(k0 + bk + 8) * ldb + bn0 + bn4];

        __syncthreads();
        As[ak + 0][ar] = a0.x; As[ak + 1][ar] = a0.y;
        As[ak + 2][ar] = a0.z; As[ak + 3][ar] = a0.w;
        As[ak + 0][ar + 64] = a1.x; As[ak + 1][ar + 64] = a1.y;
        As[ak + 2][ar + 64] = a1.z; As[ak + 3][ar + 64] = a1.w;
        *(float4*)&Bs[bk][bn4]     = b0;
        *(float4*)&Bs[bk + 8][bn4] = b1;
        __syncthreads();

#pragma unroll
        for (int kk = 0; kk < 16; ++kk) {
            float a[8], b[8];
            ((float4*)a)[0] = *(const float4*)&As[kk][ty * 8];
            ((float4*)a)[1] = *(const float4*)&As[kk][ty * 8 + 4];
            ((float4*)b)[0] = *(const float4*)&Bs[kk][tx * 8];
            ((float4*)b)[1] = *(const float4*)&Bs[kk][tx * 8 + 4];
#pragma unroll
            for (int i = 0; i < 8; ++i)
#pragma unroll
                for (int j = 0; j < 8; ++j)
                    acc[i][j] = fmaf(a[i], b[j], acc[i][j]);
        }
    }

    const int row = bm0 + ty * 8;
    const int col = bn0 + tx * 8;
#pragma unroll
    for (int i = 0; i < 8; ++i) {
        float vals[8];
#pragma unroll
        for (int j = 0; j < 8; ++j) {
            float v = acc[i][j];
            if (act == 1) {
                v += bias[col + j];
                v = (v > 20.f) ? v : log1pf(__expf(v));
            }
            vals[j] = v;
        }
        *(float4*)&C[(size_t)(row + i) * ldc + col]     = ((float4*)vals)[0];
        *(float4*)&C[(size_t)(row + i) * ldc + col + 4] = ((float4*)vals)[1];
    }
}

// ---------------------------------------------------------------------------
// Depthwise causal conv (K=3) + SiLU, fused with bf16 hi/lo split of u.
// ---------------------------------------------------------------------------
__global__ __launch_bounds__(256) void conv_silu_split(
    const float* __restrict__ xi, const float* __restrict__ cw,
    float* __restrict__ u, ushort* __restrict__ uhi, ushort* __restrict__ ulo)
{
    const int id = blockIdx.x * 256 + threadIdx.x;
    const int l = id >> 11;
    const int d = id & (D_IN - 1);
    const float w0 = cw[d * 3 + 0];
    const float w1 = cw[d * 3 + 1];
    const float w2 = cw[d * 3 + 2];
    const float x0  = xi[(size_t)l * D_IN + d];
    const float xm1 = (l >= 1) ? xi[(size_t)(l - 1) * D_IN + d] : 0.f;
    const float xm2 = (l >= 2) ? xi[(size_t)(l - 2) * D_IN + d] : 0.f;
    const float v = w0 * xm2 + w1 * xm1 + w2 * x0;
    const float s = fast_rcp(1.f + fast_exp2(-LOG2E * v));
    const float uu = v * s;
    u[id] = uu;
    const ushort h = f2bf(uu);
    uhi[id] = h;
    ulo[id] = f2bf(uu - bf2f(h));
}

// ---------------------------------------------------------------------------
// Per-chunk column sums of delta (double)
// ---------------------------------------------------------------------------
__global__ __launch_bounds__(256) void csum64(
    const float* __restrict__ delta, double* __restrict__ csum)
{
    const int d = blockIdx.x * 256 + threadIdx.x;
    const int c = blockIdx.y;
    double s = 0.0;
    for (int i = 0; i < LC; ++i)
        s += (double)delta[(size_t)(c * LC + i) * D_IN + d];
    csum[(size_t)c * D_IN + d] = s;
}

__global__ __launch_bounds__(256) void chunk_prefix(
    const double* __restrict__ csum, double* __restrict__ P0,
    double* __restrict__ Td)
{
    const int d = blockIdx.x * 256 + threadIdx.x;
    double P = 0.0;
    for (int c = 0; c < NCH; ++c) {
        P0[(size_t)c * D_IN + d] = P;
        P += csum[(size_t)c * D_IN + d];
    }
    Td[d] = P;
}

// ---------------------------------------------------------------------------
// sfx[l][d] = float(max(Td - P_inclusive(l), 0)).  (rg is now produced by
// gemm1's epilogue; this kernel no longer touches res.)
// ---------------------------------------------------------------------------
__global__ __launch_bounds__(256) void sfx_precompute(
    const float* __restrict__ delta, const double* __restrict__ P0,
    const double* __restrict__ Td, float* __restrict__ sfx)
{
    const int d = blockIdx.x * 256 + threadIdx.x;
    const int c = blockIdx.y;
    double P = P0[(size_t)c * D_IN + d];
    const double T = Td[d];
    for (int i = 0; i < LC; ++i) {
        const size_t row = (size_t)(c * LC + i) * D_IN + d;
        P += (double)delta[row];
        sfx[row] = (float)fmax(T - P, 0.0);
    }
}

// ---------------------------------------------------------------------------
// Pass A (cumsum form): Wc[c,d,n] = sum_j du[j]*B[j,n]*exp2(An2*sfx[j]).
// ---------------------------------------------------------------------------
__global__ __launch_bounds__(512) void scan_partA(
    const float* __restrict__ delta, const float* __restrict__ u,
    const float* __restrict__ sfxbuf, const float* __restrict__ xdbl,
    const float* __restrict__ Alog, float* __restrict__ Wc)
{
    __shared__ float2 spA[LC][DT];     // (delta*u, sfx)  16 KB
    __shared__ float  sBA[LC][16];     // B                4 KB

    const int t  = threadIdx.x;
    const int c  = blockIdx.x;
    const int d0 = blockIdx.y * DT;

    {
        const int r = t >> 3, c4 = (t & 7) * 4;
        const size_t row = (size_t)(c * LC + r) * D_IN + d0 + c4;
        const float4 dv4 = *(const float4*)&delta[row];
        const float4 uv4 = *(const float4*)&u[row];
        const float4 sx4 = *(const float4*)&sfxbuf[row];
        spA[r][c4 + 0] = make_float2(dv4.x * uv4.x, sx4.x);
        spA[r][c4 + 1] = make_float2(dv4.y * uv4.y, sx4.y);
        spA[r][c4 + 2] = make_float2(dv4.z * uv4.z, sx4.z);
        spA[r][c4 + 3] = make_float2(dv4.w * uv4.w, sx4.w);
    }
    if (t < 256) {
        const int r = t >> 2, c4 = (t & 3) * 4;
        *(float4*)&sBA[r][c4] =
            *(const float4*)&xdbl[(size_t)(c * LC + r) * XDBL_LD + DT_RANK + c4];
    }
    __syncthreads();

    const int n  = t & 15;
    const int dq = t >> 4;
    const int d  = d0 + dq;
    const float An2 = -expf(Alog[d * N_STATE + n]) * LOG2E;

    float W = 0.f;
#pragma unroll
    for (int i = 0; i < LC; ++i) {
        const float2 p = spA[i][dq];
        W = fmaf(p.x * sBA[i][n], fast_exp2(An2 * p.y), W);
    }
    Wc[((size_t)c * D_IN + d) * N_STATE + n] = W;
}

// ---------------------------------------------------------------------------
// Pass B: exclusive prefix over chunks (plain adds; cumsum form).
// ---------------------------------------------------------------------------
__global__ __launch_bounds__(256) void scan_combine(float* __restrict__ Wc)
{
    const int id = blockIdx.x * 256 + threadIdx.x;   // (d,n)
    float W = 0.f;
    for (int c = 0; c < NCH; ++c) {
        const size_t idx = (size_t)c * (D_IN * N_STATE) + id;
        const float w = Wc[idx];
        Wc[idx] = W;
        W += w;
    }
}

// ---------------------------------------------------------------------------
// Pass C (cumsum form): W += du*B*E; xs = W/(E+1e-12); y = sum_n xs*C; *rg.
// ---------------------------------------------------------------------------
__global__ __launch_bounds__(512) void scan_partC(
    const float* __restrict__ delta, const float* __restrict__ u,
    const float* __restrict__ xdbl, const float* __restrict__ W0buf,
    const float* __restrict__ sfxbuf, const float* __restrict__ Alog,
    const float* __restrict__ Dvec, const float* __restrict__ rgbuf,
    float* __restrict__ yg)
{
    __shared__ float4 spack[LC][DT];   // 32 KB
    __shared__ float2 sbc[LC][16];     //  8 KB

    const int t  = threadIdx.x;
    const int c  = blockIdx.x;
    const int d0 = blockIdx.y * DT;

    {
        const int r = t >> 3, c4 = (t & 7) * 4;
        const size_t row = (size_t)(c * LC + r) * D_IN + d0 + c4;
        const float4 dv4 = *(const float4*)&delta[row];
        const float4 uv4 = *(const float4*)&u[row];
        const float4 sx4 = *(const float4*)&sfxbuf[row];
        const float4 rg4 = *(const float4*)&rgbuf[row];
        spack[r][c4 + 0] = make_float4(dv4.x * uv4.x, sx4.x, uv4.x, rg4.x);
        spack[r][c4 + 1] = make_float4(dv4.y * uv4.y, sx4.y, uv4.y, rg4.y);
        spack[r][c4 + 2] = make_float4(dv4.z * uv4.z, sx4.z, uv4.z, rg4.z);
        spack[r][c4 + 3] = make_float4(dv4.w * uv4.w, sx4.w, uv4.w, rg4.w);
    }
    if (t < 256) {
        const int r = t >> 2, n4 = (t & 3) * 4;
        const float4 b4 = *(const float4*)&xdbl[(size_t)(c * LC + r) * XDBL_LD + DT_RANK + n4];
        const float4 c4v = *(const float4*)&xdbl[(size_t)(c * LC + r) * XDBL_LD + DT_RANK + 16 + n4];
        sbc[r][n4 + 0] = make_float2(b4.x, c4v.x);
        sbc[r][n4 + 1] = make_float2(b4.y, c4v.y);
        sbc[r][n4 + 2] = make_float2(b4.z, c4v.z);
        sbc[r][n4 + 3] = make_float2(b4.w, c4v.w);
    }
    __syncthreads();

    const int n  = t & 15;
    const int dq = t >> 4;
    const int d  = d0 + dq;
    const float An2 = -expf(Alog[d * N_STATE + n]) * LOG2E;
    const float Dd = Dvec[d];

    float W = W0buf[((size_t)c * D_IN + d) * N_STATE + n];

#pragma unroll
    for (int i = 0; i < LC; ++i) {
        const float4 p = spack[i][dq];
        const float2 bc = sbc[i][n];
        const float E = fast_exp2(An2 * p.y);
        W = fmaf(p.x * bc.x, E, W);
        const float xs = W * fast_rcp(E + 1e-12f);
        float contrib = xs * bc.y;
        contrib = dpp_add<0xB1>(contrib);    // quad_perm 1,0,3,2  (xor 1)
        contrib = dpp_add<0x4E>(contrib);    // quad_perm 2,3,0,1  (xor 2)
        contrib = dpp_add<0x128>(contrib);   // row_ror:8
        contrib = dpp_add<0x124>(contrib);   // row_ror:4
        if (n == 0) {
            yg[(size_t)(c * LC + i) * D_IN + d] =
                fmaf(p.z, Dd, contrib) * p.w;
        }
    }
}

// ---------------------------------------------------------------------------
// Launch.  Workspace (74.5 MB peak, time-multiplexed; ws proven >= 84.9 MB):
//   [ 0    ,16.78M): xi -> wxp -> sfx -> yg_hi/yg_lo
//   [16.78 ,33.55 ): rg (written by gemm1 epilogue) -> out partials p01
//   [33.55 ,50.33 ): x_hi/x_lo -> u (f32) -> wo_hi/wo_lo
//   [50.33 ,51.38 ): xdbl [2048][128] f32
//   [51.38 ,68.16 ): wi_hi/wi_lo -> u_hi/u_lo -> delta/yg -> p23
//   [68.16 ,73.42 ): Wc/W0, csum, P0, Td
//   [73.42 ,74.47 ): wx_hi/wx_lo
// ---------------------------------------------------------------------------
extern "C" void kernel_launch(void* const* d_in, const int* in_sizes, int n_in,
                              void* d_out, int out_size, void* d_ws, size_t ws_size,
                              hipStream_t stream)
{
    const float* x      = (const float*)d_in[0];
    const float* W_in   = (const float*)d_in[1];
    const float* conv_w = (const float*)d_in[2];
    const float* W_x    = (const float*)d_in[3];
    const float* W_del  = (const float*)d_in[4];
    const float* b_del  = (const float*)d_in[5];
    const float* A_log  = (const float*)d_in[6];
    const float* Dv     = (const float*)d_in[7];
    const float* W_out  = (const float*)d_in[8];
    float* out = (float*)d_out;

    char* ws = (char*)d_ws;
    float*  xi    = (float*)(ws + 0);
    float*  wxp   = (float*)(ws + 0);
    float*  sfx   = (float*)(ws + 0);
    ushort* yg_hi = (ushort*)(ws + 0);
    ushort* yg_lo = (ushort*)(ws + 8388608);
    float*  rg    = (float*)(ws + 16777216);   // gemm1 epilogue writes res*sigmoid(res)
    float*  p01   = (float*)(ws + 16777216);
    ushort* x_hi  = (ushort*)(ws + 33554432);
    ushort* x_lo  = (ushort*)(ws + 37748736);
    float*  u     = (float*)(ws + 33554432);
    ushort* wo_hi = (ushort*)(ws + 33554432);
    ushort* wo_lo = (ushort*)(ws + 37748736);
    float*  xdbl  = (float*)(ws + 50331648);
    ushort* wi_hi = (ushort*)(ws + 51380224);
    ushort* wi_lo = (ushort*)(ws + 59768832);
    ushort* u_hi  = (ushort*)(ws + 51380224);
    ushort* u_lo  = (ushort*)(ws + 59768832);
    float*  delta = (float*)(ws + 51380224);
    float*  p23   = (float*)(ws + 51380224);
    float*  Wc    = (float*)(ws + 68157440);   // 4.19 MB
    double* csum  = (double*)(ws + 72351744);
    double* P0    = (double*)(ws + 72876032);
    double* Td    = (double*)(ws + 73400320);
    ushort* wx_hi = (ushort*)(ws + 73416704);
    ushort* wx_lo = (ushort*)(ws + 73940992);
    float*  yg    = delta;

    // 1) W_in^T split
    split_transpose<<<dim3(4096 / 32, 1024 / 32), 256, 0, stream>>>(
        W_in, wi_hi, wi_lo, 1024, 4096);

    // 2) x split
    split_bf16<<<(SEQ * D_MODEL / 4) / 256, 256, 0, stream>>>(x, x_hi, x_lo);

    // 3) [xi | rg] = x @ W_in   (C1 path applies SiLU gate in-epilogue)
    gemm_mfma3<<<dim3(4096 / 128, 2048 / 128), 256, 0, stream>>>(
        x_hi, x_lo, wi_hi, wi_lo, xi, rg, D_IN,
        SEQ, 2 * D_IN, D_MODEL, D_IN, D_IN);

    // 4) u = silu(conv(xi)) + u hi/lo split (fused)
    conv_silu_split<<<(SEQ * D_IN) / 256, 256, 0, stream>>>(
        xi, conv_w, u, u_hi, u_lo);

    // 5) W_x^T padded split
    split_transpose_pad<<<dim3(XDBL_LD / 32, D_IN / 32), 256, 0, stream>>>(
        W_x, wx_hi, wx_lo, D_IN, XDBL_W);

    // 6) x_dbl = u @ W_x  (split-K MFMA, fixed-order reduce)
    gemm_wx_mfma<<<dim3(WX_KSPLIT, SEQ / 128), 256, 0, stream>>>(
        u_hi, u_lo, wx_hi, wx_lo, wxp);
    wx_reduce<<<(SEQ * XDBL_LD / 4) / 256, 256, 0, stream>>>(wxp, xdbl);

    // 7) delta = softplus(delta_lr @ W_delta + b_delta)
    gemm128<<<dim3(2048 / 128, 2048 / 128), 256, 0, stream>>>(
        xdbl, W_del, delta, SEQ, D_IN, DT_RANK, XDBL_LD, D_IN, D_IN,
        b_del, 1);

    // 8) chunk sums + prefix + suffix precompute (double, deterministic)
    csum64<<<dim3(D_IN / 256, NCH), 256, 0, stream>>>(delta, csum);
    chunk_prefix<<<D_IN / 256, 256, 0, stream>>>(csum, P0, Td);
    sfx_precompute<<<dim3(D_IN / 256, NCH), 256, 0, stream>>>(delta, P0, Td, sfx);

    // 9) chunk-parallel scan (cumsum form)
    scan_partA<<<dim3(NCH, D_IN / DT), 512, 0, stream>>>(
        delta, u, sfx, xdbl, A_log, Wc);
    scan_combine<<<(D_IN * N_STATE) / 256, 256, 0, stream>>>(Wc);
    scan_partC<<<dim3(NCH, D_IN / DT), 512, 0, stream>>>(
        delta, u, xdbl, Wc, sfx, A_log, Dv, rg, yg);

    // 10) yg split (sfx dead; region reused)
    split_bf16<<<(SEQ * D_IN / 4) / 256, 256, 0, stream>>>(yg, yg_hi, yg_lo);

    // 11) W_out^T split (u dead; region reused)
    split_transpose<<<dim3(1024 / 32, 2048 / 32), 256, 0, stream>>>(
        W_out, wo_hi, wo_lo, 2048, 1024);

    // 12) out = yg @ W_out  (split-K=4; partials in dead regions)
    gemm_out_mfma<<<dim3(D_MODEL / 128, SEQ / 128, OUT_KSPLIT), 256, 0, stream>>>(
        yg_hi, yg_lo, wo_hi, wo_lo, p01, p23);
    out_reduce<<<(SEQ * D_MODEL / 4) / 256, 256, 0, stream>>>(p01, p23, out);
}

// Round 13
// 240.006 us; speedup vs baseline: 1.2263x; 1.0679x over previous
//
#include <hip/hip_runtime.h>
#include <hip/hip_bf16.h>
#include <math.h>

// ---------------------------------------------------------------------------
// Shapes (compile-time constants for this problem)
// ---------------------------------------------------------------------------
#define SEQ     2048
#define D_MODEL 1024
#define D_IN    2048
#define N_STATE 16
#define DT_RANK 64
#define XDBL_W  96          // DT_RANK + 2*N_STATE
#define XDBL_LD 128         // padded leading dim of x_dbl
#define LC      64          // scan chunk length
#define NCH     32          // SEQ / LC
#define DT      32          // d-channels per scan block
#define WX_KSPLIT 16
#define WX_KSEG   (D_IN / WX_KSPLIT)   // 128
#define OUT_KSPLIT 4
#define OUT_KSEG   (D_IN / OUT_KSPLIT) // 512

#define LOG2E   1.4426950408889634f

typedef __attribute__((ext_vector_type(8))) _Float16 f16x8;
typedef __attribute__((ext_vector_type(4))) float f32x4;

__device__ __forceinline__ float fast_exp2(float x) { return __builtin_amdgcn_exp2f(x); }
__device__ __forceinline__ float fast_rcp(float x)  { return __builtin_amdgcn_rcpf(x); }

// fp32 <-> fp16 (RNE)
__device__ __forceinline__ ushort f2h(float x) {
    _Float16 h = (_Float16)x;
    return __builtin_bit_cast(ushort, h);
}
__device__ __forceinline__ float h2f(ushort u) {
    return (float)__builtin_bit_cast(_Float16, u);
}

// async global->LDS, 16 bytes/lane; LDS dest = wave-uniform base + lane*16.
__device__ __forceinline__ void gload16(const ushort* g, ushort* l) {
    __builtin_amdgcn_global_load_lds(
        (const __attribute__((address_space(1))) void*)g,
        (__attribute__((address_space(3))) void*)l, 16, 0, 0);
}

// Pre-swizzled-source staging: LDS linear (slot idx = q*256 + wave*64 + lane),
// each lane fetches global col-block (lane&7)^(lane>>3) so LDS holds the
// XOR-swizzled layout ( [r][ (kc^(r&7))*8 ] ) the MFMA ds_read_b128 expects.
#define GL_DEFS                                                                \
    const int lane8 = lane >> 3;                                               \
    const int scol  = (lane & 7) ^ lane8;                                      \
    const int wq    = wave * 8;

#define STAGE_GL(SRC, DST, BASE, LDK, KOFF)                                    \
    _Pragma("unroll")                                                          \
    for (int q = 0; q < 4; ++q) {                                              \
        const int rr = q * 32 + wq + lane8;                                    \
        gload16(&SRC[(size_t)((BASE) + rr) * (LDK) + (KOFF) + scol * 8],       \
                ((ushort*)DST) + (q * 256 + wave * 64) * 8);                   \
    }

// fp16 2-pass inner compute for one 32-K slice (ks = 0/1):
// acc += Ah*B + Al*B   (A = Ah+Al covers 22 mantissa bits; B single fp16)
#define COMPUTE_KS(KS)                                                         \
    {                                                                          \
        const int slot = ((((KS) << 2) | l4) ^ sw) * 8;                        \
        f16x8 ah[4], al[4], bb[4];                                             \
        _Pragma("unroll")                                                      \
        for (int f = 0; f < 4; ++f) {                                          \
            const int ar = mw + f * 16 + l15;                                  \
            const int br = nw + f * 16 + l15;                                  \
            ah[f] = *(const f16x8*)&lA[0][ar][slot];                           \
            al[f] = *(const f16x8*)&lA[1][ar][slot];                           \
            bb[f] = *(const f16x8*)&lB[br][slot];                              \
        }                                                                      \
        _Pragma("unroll")                                                      \
        for (int i = 0; i < 4; ++i)                                            \
            _Pragma("unroll")                                                  \
            for (int j = 0; j < 4; ++j) {                                      \
                acc[i][j] = __builtin_amdgcn_mfma_f32_16x16x32_f16(            \
                    ah[i], bb[j], acc[i][j], 0, 0, 0);                         \
                acc[i][j] = __builtin_amdgcn_mfma_f32_16x16x32_f16(            \
                    al[i], bb[j], acc[i][j], 0, 0, 0);                         \
            }                                                                  \
    }

// v_add_f32 with DPP-moved operand: 16-lane butterfly without the DS pipe.
template <int CTRL>
__device__ __forceinline__ float dpp_add(float x) {
    int y = __builtin_amdgcn_update_dpp(0, __float_as_int(x), CTRL, 0xF, 0xF, true);
    return x + __int_as_float(y);
}

// ---------------------------------------------------------------------------
// split fp32 -> fp16 hi/lo (elementwise). One float4 per thread.
// ---------------------------------------------------------------------------
__global__ __launch_bounds__(256) void split_f16(
    const float* __restrict__ in, ushort* __restrict__ hi,
    ushort* __restrict__ lo)
{
    const int i = blockIdx.x * 256 + threadIdx.x;
    const float4 v = *(const float4*)&in[(size_t)i * 4];
    ushort4 h, l;
    h.x = f2h(v.x); l.x = f2h(v.x - h2f(h.x));
    h.y = f2h(v.y); l.y = f2h(v.y - h2f(h.y));
    h.z = f2h(v.z); l.z = f2h(v.z - h2f(h.z));
    h.w = f2h(v.w); l.w = f2h(v.w - h2f(h.w));
    *(ushort4*)&hi[(size_t)i * 4] = h;
    *(ushort4*)&lo[(size_t)i * 4] = l;
}

// ---------------------------------------------------------------------------
// transpose + fp16 convert: in[R][C] fp32 -> out[C][R] fp16 (single plane).
// ---------------------------------------------------------------------------
__global__ __launch_bounds__(256) void trans_f16(
    const float* __restrict__ in, ushort* __restrict__ out, int R, int C)
{
    __shared__ float tile[32][33];
    const int c0 = blockIdx.x * 32;
    const int r0 = blockIdx.y * 32;
    const int tc = threadIdx.x & 31;
    const int tr = threadIdx.x >> 5;
#pragma unroll
    for (int q = 0; q < 4; ++q)
        tile[tr + 8 * q][tc] = in[(size_t)(r0 + tr + 8 * q) * C + c0 + tc];
    __syncthreads();
#pragma unroll
    for (int q = 0; q < 4; ++q)
        out[(size_t)(c0 + tr + 8 * q) * R + r0 + tc] = f2h(tile[tc][tr + 8 * q]);
}

// transpose + fp16 convert with zero padding on the output-row axis.
__global__ __launch_bounds__(256) void trans_f16_pad(
    const float* __restrict__ in, ushort* __restrict__ out, int R, int Csrc)
{
    __shared__ float tile[32][33];
    const int c0 = blockIdx.x * 32;
    const int r0 = blockIdx.y * 32;
    const int tc = threadIdx.x & 31;
    const int tr = threadIdx.x >> 5;
#pragma unroll
    for (int q = 0; q < 4; ++q) {
        const int c = c0 + tc;
        tile[tr + 8 * q][tc] =
            (c < Csrc) ? in[(size_t)(r0 + tr + 8 * q) * Csrc + c] : 0.f;
    }
    __syncthreads();
#pragma unroll
    for (int q = 0; q < 4; ++q)
        out[(size_t)(c0 + tr + 8 * q) * R + r0 + tc] = f2h(tile[tc][tr + 8 * q]);
}

// ---------------------------------------------------------------------------
// fp16 2-pass MFMA GEMM (A row-major hi/lo fp16, B transposed single fp16).
// Tile 128x128, K-step 64, 4 waves, 48 KB LDS (3 blocks/CU).
// C1 epilogue applies SiLU gate: stores v*sigmoid(v) (res -> rg fused).
// ---------------------------------------------------------------------------
__global__ __launch_bounds__(256) void gemm_mfma3(
    const ushort* __restrict__ Ahi, const ushort* __restrict__ Alo,
    const ushort* __restrict__ Bf,
    float* __restrict__ C0, float* __restrict__ C1, int nsplit,
    int M, int N, int K, int ldc0, int ldc1)
{
    __shared__ ushort lA[2][128][64];   // 32 KB
    __shared__ ushort lB[128][64];      // 16 KB

    const int t    = threadIdx.x;
    const int m0   = blockIdx.y * 128;
    const int n0   = blockIdx.x * 128;
    const int wave = t >> 6;
    const int lane = t & 63;
    const int mw   = (wave & 1) * 64;
    const int nw   = (wave >> 1) * 64;
    const int l15  = lane & 15;
    const int l4   = lane >> 4;
    const int sw   = l15 & 7;
    GL_DEFS

    f32x4 acc[4][4];
#pragma unroll
    for (int i = 0; i < 4; ++i)
#pragma unroll
        for (int j = 0; j < 4; ++j)
            acc[i][j] = (f32x4){0.f, 0.f, 0.f, 0.f};

    for (int k0 = 0; k0 < K; k0 += 64) {
        __syncthreads();
        STAGE_GL(Ahi, lA[0], m0, K, k0)
        STAGE_GL(Alo, lA[1], m0, K, k0)
        STAGE_GL(Bf,  lB,    n0, K, k0)
        __syncthreads();
        COMPUTE_KS(0)
        COMPUTE_KS(1)
    }

#pragma unroll
    for (int i = 0; i < 4; ++i) {
        const int rowg = m0 + mw + i * 16 + l4 * 4;
#pragma unroll
        for (int j = 0; j < 4; ++j) {
            const int colg = n0 + nw + j * 16 + l15;
            if (colg < nsplit) {
#pragma unroll
                for (int v = 0; v < 4; ++v)
                    C0[(size_t)(rowg + v) * ldc0 + colg] = acc[i][j][v];
            } else {
                const int cc = colg - nsplit;
#pragma unroll
                for (int v = 0; v < 4; ++v) {
                    const float r = acc[i][j][v];
                    C1[(size_t)(rowg + v) * ldc1 + cc] =
                        r * fast_rcp(1.f + fast_exp2(-LOG2E * r));
                }
            }
        }
    }
}

// ---------------------------------------------------------------------------
// split-K MFMA GEMM for x_dbl = u @ W_x (N padded 96->128), fp16 2-pass.
// ---------------------------------------------------------------------------
__global__ __launch_bounds__(256) void gemm_wx_mfma(
    const ushort* __restrict__ Ahi, const ushort* __restrict__ Alo,
    const ushort* __restrict__ Bf, float* __restrict__ part)
{
    __shared__ ushort lA[2][128][64];
    __shared__ ushort lB[128][64];

    const int t    = threadIdx.x;
    const int kb   = blockIdx.x;
    const int m0   = blockIdx.y * 128;
    const int wave = t >> 6;
    const int lane = t & 63;
    const int mw   = (wave & 1) * 64;
    const int nw   = (wave >> 1) * 64;
    const int l15  = lane & 15;
    const int l4   = lane >> 4;
    const int sw   = l15 & 7;
    const int kbase = kb * WX_KSEG;
    GL_DEFS

    f32x4 acc[4][4];
#pragma unroll
    for (int i = 0; i < 4; ++i)
#pragma unroll
        for (int j = 0; j < 4; ++j)
            acc[i][j] = (f32x4){0.f, 0.f, 0.f, 0.f};

    for (int k0 = 0; k0 < WX_KSEG; k0 += 64) {
        __syncthreads();
        STAGE_GL(Ahi, lA[0], m0, D_IN, kbase + k0)
        STAGE_GL(Alo, lA[1], m0, D_IN, kbase + k0)
        STAGE_GL(Bf,  lB,    0,  D_IN, kbase + k0)
        __syncthreads();
        COMPUTE_KS(0)
        COMPUTE_KS(1)
    }

#pragma unroll
    for (int i = 0; i < 4; ++i) {
        const int rowg = m0 + mw + i * 16 + l4 * 4;
#pragma unroll
        for (int j = 0; j < 4; ++j) {
            const int colg = nw + j * 16 + l15;
#pragma unroll
            for (int v = 0; v < 4; ++v)
                part[((size_t)kb * SEQ + rowg + v) * XDBL_LD + colg] =
                    acc[i][j][v];
        }
    }
}

// Fixed-order reduction of the WX_KSPLIT partials -> xdbl [SEQ][XDBL_LD].
__global__ __launch_bounds__(256) void wx_reduce(
    const float* __restrict__ part, float* __restrict__ xdbl)
{
    const size_t i = (size_t)(blockIdx.x * 256 + threadIdx.x) * 4;
    float4 s = *(const float4*)&part[i];
#pragma unroll
    for (int kb = 1; kb < WX_KSPLIT; ++kb) {
        const float4 v = *(const float4*)&part[(size_t)kb * SEQ * XDBL_LD + i];
        s.x += v.x; s.y += v.y; s.z += v.z; s.w += v.w;
    }
    *(float4*)&xdbl[i] = s;
}

// ---------------------------------------------------------------------------
// split-K=4 MFMA GEMM for out = yg @ W_out, fp16 2-pass.
// ---------------------------------------------------------------------------
__global__ __launch_bounds__(256) void gemm_out_mfma(
    const ushort* __restrict__ Ahi, const ushort* __restrict__ Alo,
    const ushort* __restrict__ Bf,
    float* __restrict__ p01, float* __restrict__ p23)
{
    __shared__ ushort lA[2][128][64];
    __shared__ ushort lB[128][64];

    const int t    = threadIdx.x;
    const int n0   = blockIdx.x * 128;
    const int m0   = blockIdx.y * 128;
    const int kb   = blockIdx.z;
    const int wave = t >> 6;
    const int lane = t & 63;
    const int mw   = (wave & 1) * 64;
    const int nw   = (wave >> 1) * 64;
    const int l15  = lane & 15;
    const int l4   = lane >> 4;
    const int sw   = l15 & 7;
    const int kbase = kb * OUT_KSEG;
    GL_DEFS

    f32x4 acc[4][4];
#pragma unroll
    for (int i = 0; i < 4; ++i)
#pragma unroll
        for (int j = 0; j < 4; ++j)
            acc[i][j] = (f32x4){0.f, 0.f, 0.f, 0.f};

    for (int k0 = 0; k0 < OUT_KSEG; k0 += 64) {
        __syncthreads();
        STAGE_GL(Ahi, lA[0], m0, D_IN, kbase + k0)
        STAGE_GL(Alo, lA[1], m0, D_IN, kbase + k0)
        STAGE_GL(Bf,  lB,    n0, D_IN, kbase + k0)
        __syncthreads();
        COMPUTE_KS(0)
        COMPUTE_KS(1)
    }

    float* base = (kb & 2) ? p23 : p01;
    base += (size_t)(kb & 1) * SEQ * D_MODEL;
#pragma unroll
    for (int i = 0; i < 4; ++i) {
        const int rowg = m0 + mw + i * 16 + l4 * 4;
#pragma unroll
        for (int j = 0; j < 4; ++j) {
            const int colg = n0 + nw + j * 16 + l15;
#pragma unroll
            for (int v = 0; v < 4; ++v)
                base[(size_t)(rowg + v) * D_MODEL + colg] = acc[i][j][v];
        }
    }
}

// Fixed-order reduce of the 4 output partials -> out [SEQ][D_MODEL].
__global__ __launch_bounds__(256) void out_reduce(
    const float* __restrict__ p01, const float* __restrict__ p23,
    float* __restrict__ out)
{
    const size_t i = (size_t)(blockIdx.x * 256 + threadIdx.x) * 4;
    const size_t MN = (size_t)SEQ * D_MODEL;
    const float4 a = *(const float4*)&p01[i];
    const float4 b = *(const float4*)&p01[i + MN];
    const float4 c = *(const float4*)&p23[i];
    const float4 d = *(const float4*)&p23[i + MN];
    float4 s;
    s.x = ((a.x + b.x) + c.x) + d.x;
    s.y = ((a.y + b.y) + c.y) + d.y;
    s.z = ((a.z + b.z) + c.z) + d.z;
    s.w = ((a.w + b.w) + c.w) + d.w;
    *(float4*)&out[i] = s;
}

// ---------------------------------------------------------------------------
// fp32 tiled GEMM (small delta GEMM, K=64)
// ---------------------------------------------------------------------------
__global__ __launch_bounds__(256) void gemm128(
    const float* __restrict__ A, const float* __restrict__ B,
    float* __restrict__ C, int M, int N, int K,
    int lda, int ldb, int ldc,
    const float* __restrict__ bias, int act)
{
    __shared__ float As[16][132];
    __shared__ float Bs[16][132];

    const int t   = threadIdx.x;
    const int bn0 = blockIdx.x * 128;
    const int bm0 = blockIdx.y * 128;
    const int tx  = t & 15;
    const int ty  = t >> 4;

    const int ar  = t >> 2;
    const int ak  = (t & 3) * 4;
    const int bk  = t >> 5;
    const int bn4 = (t & 31) * 4;

    float acc[8][8];
#pragma unroll
    for (int i = 0; i < 8; ++i)
#pragma unroll
        for (int j = 0; j < 8; ++j) acc[i][j] = 0.f;

    for (int k0 = 0; k0 < K; k0 += 16) {
        float4 a0 = *(const float4*)&A[(size_t)(bm0 + ar)      * lda + k0 + ak];
        float4 a1 = *(const float4*)&A[(size_t)(bm0 + ar + 64) * lda + k0 + ak];
        float4 b0 = *(const float4*)&B[(size_t)(k0 + bk)     * ldb + bn0 + bn4];
        float4 b1 = *(const float4*)&B[(size_t)(k0 + bk + 8) * ldb + bn0 + bn4];

        __syncthreads();
        As[ak + 0][ar] = a0.x; As[ak + 1][ar] = a0.y;
        As[ak + 2][ar] = a0.z; As[ak + 3][ar] = a0.w;
        As[ak + 0][ar + 64] = a1.x; As[ak + 1][ar + 64] = a1.y;
        As[ak + 2][ar + 64] = a1.z; As[ak + 3][ar + 64] = a1.w;
        *(float4*)&Bs[bk][bn4]     = b0;
        *(float4*)&Bs[bk + 8][bn4] = b1;
        __syncthreads();

#pragma unroll
        for (int kk = 0; kk < 16; ++kk) {
            float a[8], b[8];
            ((float4*)a)[0] = *(const float4*)&As[kk][ty * 8];
            ((float4*)a)[1] = *(const float4*)&As[kk][ty * 8 + 4];
            ((float4*)b)[0] = *(const float4*)&Bs[kk][tx * 8];
            ((float4*)b)[1] = *(const float4*)&Bs[kk][tx * 8 + 4];
#pragma unroll
            for (int i = 0; i < 8; ++i)
#pragma unroll
                for (int j = 0; j < 8; ++j)
                    acc[i][j] = fmaf(a[i], b[j], acc[i][j]);
        }
    }

    const int row = bm0 + ty * 8;
    const int col = bn0 + tx * 8;
#pragma unroll
    for (int i = 0; i < 8; ++i) {
        float vals[8];
#pragma unroll
        for (int j = 0; j < 8; ++j) {
            float v = acc[i][j];
            if (act == 1) {
                v += bias[col + j];
                v = (v > 20.f) ? v : log1pf(__expf(v));
            }
            vals[j] = v;
        }
        *(float4*)&C[(size_t)(row + i) * ldc + col]     = ((float4*)vals)[0];
        *(float4*)&C[(size_t)(row + i) * ldc + col + 4] = ((float4*)vals)[1];
    }
}

// ---------------------------------------------------------------------------
// Depthwise causal conv (K=3) + SiLU, fused with fp16 hi/lo split of u.
// ---------------------------------------------------------------------------
__global__ __launch_bounds__(256) void conv_silu_split(
    const float* __restrict__ xi, const float* __restrict__ cw,
    float* __restrict__ u, ushort* __restrict__ uhi, ushort* __restrict__ ulo)
{
    const int id = blockIdx.x * 256 + threadIdx.x;
    const int l = id >> 11;
    const int d = id & (D_IN - 1);
    const float w0 = cw[d * 3 + 0];
    const float w1 = cw[d * 3 + 1];
    const float w2 = cw[d * 3 + 2];
    const float x0  = xi[(size_t)l * D_IN + d];
    const float xm1 = (l >= 1) ? xi[(size_t)(l - 1) * D_IN + d] : 0.f;
    const float xm2 = (l >= 2) ? xi[(size_t)(l - 2) * D_IN + d] : 0.f;
    const float v = w0 * xm2 + w1 * xm1 + w2 * x0;
    const float s = fast_rcp(1.f + fast_exp2(-LOG2E * v));
    const float uu = v * s;
    u[id] = uu;
    const ushort h = f2h(uu);
    uhi[id] = h;
    ulo[id] = f2h(uu - h2f(h));
}

// ---------------------------------------------------------------------------
// Per-chunk column sums of delta (double)
// ---------------------------------------------------------------------------
__global__ __launch_bounds__(256) void csum64(
    const float* __restrict__ delta, double* __restrict__ csum)
{
    const int d = blockIdx.x * 256 + threadIdx.x;
    const int c = blockIdx.y;
    double s = 0.0;
    for (int i = 0; i < LC; ++i)
        s += (double)delta[(size_t)(c * LC + i) * D_IN + d];
    csum[(size_t)c * D_IN + d] = s;
}

__global__ __launch_bounds__(256) void chunk_prefix(
    const double* __restrict__ csum, double* __restrict__ P0,
    double* __restrict__ Td)
{
    const int d = blockIdx.x * 256 + threadIdx.x;
    double P = 0.0;
    for (int c = 0; c < NCH; ++c) {
        P0[(size_t)c * D_IN + d] = P;
        P += csum[(size_t)c * D_IN + d];
    }
    Td[d] = P;
}

// ---------------------------------------------------------------------------
// sfx[l][d] = float(max(Td - P_inclusive(l), 0)).
// ---------------------------------------------------------------------------
__global__ __launch_bounds__(256) void sfx_precompute(
    const float* __restrict__ delta, const double* __restrict__ P0,
    const double* __restrict__ Td, float* __restrict__ sfx)
{
    const int d = blockIdx.x * 256 + threadIdx.x;
    const int c = blockIdx.y;
    double P = P0[(size_t)c * D_IN + d];
    const double T = Td[d];
    for (int i = 0; i < LC; ++i) {
        const size_t row = (size_t)(c * LC + i) * D_IN + d;
        P += (double)delta[row];
        sfx[row] = (float)fmax(T - P, 0.0);
    }
}

// ---------------------------------------------------------------------------
// Pass A (cumsum form): Wc[c,d,n] = sum_j du[j]*B[j,n]*exp2(An2*sfx[j]).
// ---------------------------------------------------------------------------
__global__ __launch_bounds__(512) void scan_partA(
    const float* __restrict__ delta, const float* __restrict__ u,
    const float* __restrict__ sfxbuf, const float* __restrict__ xdbl,
    const float* __restrict__ Alog, float* __restrict__ Wc)
{
    __shared__ float2 spA[LC][DT];     // (delta*u, sfx)  16 KB
    __shared__ float  sBA[LC][16];     // B                4 KB

    const int t  = threadIdx.x;
    const int c  = blockIdx.x;
    const int d0 = blockIdx.y * DT;

    {
        const int r = t >> 3, c4 = (t & 7) * 4;
        const size_t row = (size_t)(c * LC + r) * D_IN + d0 + c4;
        const float4 dv4 = *(const float4*)&delta[row];
        const float4 uv4 = *(const float4*)&u[row];
        const float4 sx4 = *(const float4*)&sfxbuf[row];
        spA[r][c4 + 0] = make_float2(dv4.x * uv4.x, sx4.x);
        spA[r][c4 + 1] = make_float2(dv4.y * uv4.y, sx4.y);
        spA[r][c4 + 2] = make_float2(dv4.z * uv4.z, sx4.z);
        spA[r][c4 + 3] = make_float2(dv4.w * uv4.w, sx4.w);
    }
    if (t < 256) {
        const int r = t >> 2, c4 = (t & 3) * 4;
        *(float4*)&sBA[r][c4] =
            *(const float4*)&xdbl[(size_t)(c * LC + r) * XDBL_LD + DT_RANK + c4];
    }
    __syncthreads();

    const int n  = t & 15;
    const int dq = t >> 4;
    const int d  = d0 + dq;
    const float An2 = -expf(Alog[d * N_STATE + n]) * LOG2E;

    float W = 0.f;
#pragma unroll
    for (int i = 0; i < LC; ++i) {
        const float2 p = spA[i][dq];
        W = fmaf(p.x * sBA[i][n], fast_exp2(An2 * p.y), W);
    }
    Wc[((size_t)c * D_IN + d) * N_STATE + n] = W;
}

// ---------------------------------------------------------------------------
// Pass B: exclusive prefix over chunks (plain adds; cumsum form).
// ---------------------------------------------------------------------------
__global__ __launch_bounds__(256) void scan_combine(float* __restrict__ Wc)
{
    const int id = blockIdx.x * 256 + threadIdx.x;   // (d,n)
    float W = 0.f;
    for (int c = 0; c < NCH; ++c) {
        const size_t idx = (size_t)c * (D_IN * N_STATE) + id;
        const float w = Wc[idx];
        Wc[idx] = W;
        W += w;
    }
}

// ---------------------------------------------------------------------------
// Pass C (cumsum form): W += du*B*E; xs = W/(E+1e-12); y = sum_n xs*C; *rg.
// ---------------------------------------------------------------------------
__global__ __launch_bounds__(512) void scan_partC(
    const float* __restrict__ delta, const float* __restrict__ u,
    const float* __restrict__ xdbl, const float* __restrict__ W0buf,
    const float* __restrict__ sfxbuf, const float* __restrict__ Alog,
    const float* __restrict__ Dvec, const float* __restrict__ rgbuf,
    float* __restrict__ yg)
{
    __shared__ float4 spack[LC][DT];   // 32 KB
    __shared__ float2 sbc[LC][16];     //  8 KB

    const int t  = threadIdx.x;
    const int c  = blockIdx.x;
    const int d0 = blockIdx.y * DT;

    {
        const int r = t >> 3, c4 = (t & 7) * 4;
        const size_t row = (size_t)(c * LC + r) * D_IN + d0 + c4;
        const float4 dv4 = *(const float4*)&delta[row];
        const float4 uv4 = *(const float4*)&u[row];
        const float4 sx4 = *(const float4*)&sfxbuf[row];
        const float4 rg4 = *(const float4*)&rgbuf[row];
        spack[r][c4 + 0] = make_float4(dv4.x * uv4.x, sx4.x, uv4.x, rg4.x);
        spack[r][c4 + 1] = make_float4(dv4.y * uv4.y, sx4.y, uv4.y, rg4.y);
        spack[r][c4 + 2] = make_float4(dv4.z * uv4.z, sx4.z, uv4.z, rg4.z);
        spack[r][c4 + 3] = make_float4(dv4.w * uv4.w, sx4.w, uv4.w, rg4.w);
    }
    if (t < 256) {
        const int r = t >> 2, n4 = (t & 3) * 4;
        const float4 b4 = *(const float4*)&xdbl[(size_t)(c * LC + r) * XDBL_LD + DT_RANK + n4];
        const float4 c4v = *(const float4*)&xdbl[(size_t)(c * LC + r) * XDBL_LD + DT_RANK + 16 + n4];
        sbc[r][n4 + 0] = make_float2(b4.x, c4v.x);
        sbc[r][n4 + 1] = make_float2(b4.y, c4v.y);
        sbc[r][n4 + 2] = make_float2(b4.z, c4v.z);
        sbc[r][n4 + 3] = make_float2(b4.w, c4v.w);
    }
    __syncthreads();

    const int n  = t & 15;
    const int dq = t >> 4;
    const int d  = d0 + dq;
    const float An2 = -expf(Alog[d * N_STATE + n]) * LOG2E;
    const float Dd = Dvec[d];

    float W = W0buf[((size_t)c * D_IN + d) * N_STATE + n];

#pragma unroll
    for (int i = 0; i < LC; ++i) {
        const float4 p = spack[i][dq];
        const float2 bc = sbc[i][n];
        const float E = fast_exp2(An2 * p.y);
        W = fmaf(p.x * bc.x, E, W);
        const float xs = W * fast_rcp(E + 1e-12f);
        float contrib = xs * bc.y;
        contrib = dpp_add<0xB1>(contrib);    // quad_perm 1,0,3,2  (xor 1)
        contrib = dpp_add<0x4E>(contrib);    // quad_perm 2,3,0,1  (xor 2)
        contrib = dpp_add<0x128>(contrib);   // row_ror:8
        contrib = dpp_add<0x124>(contrib);   // row_ror:4
        if (n == 0) {
            yg[(size_t)(c * LC + i) * D_IN + d] =
                fmaf(p.z, Dd, contrib) * p.w;
        }
    }
}

// ---------------------------------------------------------------------------
// Launch.  Workspace (74.5 MB peak, time-multiplexed; ws proven >= 84.9 MB):
//   [ 0    ,16.78M): xi -> wxp -> sfx -> yg_hi/yg_lo
//   [16.78 ,33.55 ): rg (gemm1 epilogue) -> out partials p01
//   [33.55 ,50.33 ): x_hi/x_lo -> u (f32) -> wo (fp16)
//   [50.33 ,51.38 ): xdbl [2048][128] f32
//   [51.38 ,68.16 ): wi (fp16 8.4MB) -> u_hi/u_lo -> delta/yg -> p23
//   [68.16 ,73.42 ): Wc/W0, csum, P0, Td
//   [73.42 ,74.47 ): wx (fp16)
// ---------------------------------------------------------------------------
extern "C" void kernel_launch(void* const* d_in, const int* in_sizes, int n_in,
                              void* d_out, int out_size, void* d_ws, size_t ws_size,
                              hipStream_t stream)
{
    const float* x      = (const float*)d_in[0];
    const float* W_in   = (const float*)d_in[1];
    const float* conv_w = (const float*)d_in[2];
    const float* W_x    = (const float*)d_in[3];
    const float* W_del  = (const float*)d_in[4];
    const float* b_del  = (const float*)d_in[5];
    const float* A_log  = (const float*)d_in[6];
    const float* Dv     = (const float*)d_in[7];
    const float* W_out  = (const float*)d_in[8];
    float* out = (float*)d_out;

    char* ws = (char*)d_ws;
    float*  xi    = (float*)(ws + 0);
    float*  wxp   = (float*)(ws + 0);
    float*  sfx   = (float*)(ws + 0);
    ushort* yg_hi = (ushort*)(ws + 0);
    ushort* yg_lo = (ushort*)(ws + 8388608);
    float*  rg    = (float*)(ws + 16777216);   // gemm1 epilogue: res*sigmoid(res)
    float*  p01   = (float*)(ws + 16777216);
    ushort* x_hi  = (ushort*)(ws + 33554432);
    ushort* x_lo  = (ushort*)(ws + 37748736);
    float*  u     = (float*)(ws + 33554432);
    ushort* wo    = (ushort*)(ws + 33554432);  // [1024][2048] fp16, 4 MB
    float*  xdbl  = (float*)(ws + 50331648);
    ushort* wi    = (ushort*)(ws + 51380224);  // [4096][1024] fp16, 8.4 MB
    ushort* u_hi  = (ushort*)(ws + 51380224);
    ushort* u_lo  = (ushort*)(ws + 59768832);
    float*  delta = (float*)(ws + 51380224);
    float*  p23   = (float*)(ws + 51380224);
    float*  Wc    = (float*)(ws + 68157440);   // 4.19 MB
    double* csum  = (double*)(ws + 72351744);
    double* P0    = (double*)(ws + 72876032);
    double* Td    = (double*)(ws + 73400320);
    ushort* wx    = (ushort*)(ws + 73416704);  // [128][2048] fp16, 0.5 MB
    float*  yg    = delta;

    // 1) W_in^T -> fp16
    trans_f16<<<dim3(4096 / 32, 1024 / 32), 256, 0, stream>>>(
        W_in, wi, 1024, 4096);

    // 2) x -> fp16 hi/lo
    split_f16<<<(SEQ * D_MODEL / 4) / 256, 256, 0, stream>>>(x, x_hi, x_lo);

    // 3) [xi | rg] = x @ W_in   (fp16 2-pass; C1 applies SiLU gate)
    gemm_mfma3<<<dim3(4096 / 128, 2048 / 128), 256, 0, stream>>>(
        x_hi, x_lo, wi, xi, rg, D_IN,
        SEQ, 2 * D_IN, D_MODEL, D_IN, D_IN);

    // 4) u = silu(conv(xi)) + u fp16 hi/lo (fused)
    conv_silu_split<<<(SEQ * D_IN) / 256, 256, 0, stream>>>(
        xi, conv_w, u, u_hi, u_lo);

    // 5) W_x^T padded -> fp16
    trans_f16_pad<<<dim3(XDBL_LD / 32, D_IN / 32), 256, 0, stream>>>(
        W_x, wx, D_IN, XDBL_W);

    // 6) x_dbl = u @ W_x  (split-K fp16 2-pass, fixed-order reduce)
    gemm_wx_mfma<<<dim3(WX_KSPLIT, SEQ / 128), 256, 0, stream>>>(
        u_hi, u_lo, wx, wxp);
    wx_reduce<<<(SEQ * XDBL_LD / 4) / 256, 256, 0, stream>>>(wxp, xdbl);

    // 7) delta = softplus(delta_lr @ W_delta + b_delta)
    gemm128<<<dim3(2048 / 128, 2048 / 128), 256, 0, stream>>>(
        xdbl, W_del, delta, SEQ, D_IN, DT_RANK, XDBL_LD, D_IN, D_IN,
        b_del, 1);

    // 8) chunk sums + prefix + suffix precompute (double, deterministic)
    csum64<<<dim3(D_IN / 256, NCH), 256, 0, stream>>>(delta, csum);
    chunk_prefix<<<D_IN / 256, 256, 0, stream>>>(csum, P0, Td);
    sfx_precompute<<<dim3(D_IN / 256, NCH), 256, 0, stream>>>(delta, P0, Td, sfx);

    // 9) chunk-parallel scan (cumsum form)
    scan_partA<<<dim3(NCH, D_IN / DT), 512, 0, stream>>>(
        delta, u, sfx, xdbl, A_log, Wc);
    scan_combine<<<(D_IN * N_STATE) / 256, 256, 0, stream>>>(Wc);
    scan_partC<<<dim3(NCH, D_IN / DT), 512, 0, stream>>>(
        delta, u, xdbl, Wc, sfx, A_log, Dv, rg, yg);

    // 10) yg -> fp16 hi/lo (sfx dead; region reused)
    split_f16<<<(SEQ * D_IN / 4) / 256, 256, 0, stream>>>(yg, yg_hi, yg_lo);

    // 11) W_out^T -> fp16 (u dead; region reused)
    trans_f16<<<dim3(1024 / 32, 2048 / 32), 256, 0, stream>>>(
        W_out, wo, 2048, 1024);

    // 12) out = yg @ W_out  (split-K=4 fp16 2-pass; partials in dead regions)
    gemm_out_mfma<<<dim3(D_MODEL / 128, SEQ / 128, OUT_KSPLIT), 256, 0, stream>>>(
        yg_hi, yg_lo, wo, p01, p23);
    out_reduce<<<(SEQ * D_MODEL / 4) / 256, 256, 0, stream>>>(p01, p23, out);
}

// Round 14
// 225.853 us; speedup vs baseline: 1.3031x; 1.0627x over previous
//
#include <hip/hip_runtime.h>
#include <hip/hip_bf16.h>
#include <math.h>

// ---------------------------------------------------------------------------
// Shapes (compile-time constants for this problem)
// ---------------------------------------------------------------------------
#define SEQ     2048
#define D_MODEL 1024
#define D_IN    2048
#define N_STATE 16
#define DT_RANK 64
#define XDBL_W  96          // DT_RANK + 2*N_STATE
#define XDBL_LD 128         // padded leading dim of x_dbl
#define LC      64          // scan chunk length
#define NCH     32          // SEQ / LC
#define DT      32          // d-channels per scan block
#define WX_KSPLIT 16
#define WX_KSEG   (D_IN / WX_KSPLIT)   // 128
#define OUT_KSPLIT 4
#define OUT_KSEG   (D_IN / OUT_KSPLIT) // 512

#define LOG2E   1.4426950408889634f

typedef __attribute__((ext_vector_type(8))) _Float16 f16x8;
typedef __attribute__((ext_vector_type(4))) float f32x4;

__device__ __forceinline__ float fast_exp2(float x) { return __builtin_amdgcn_exp2f(x); }
__device__ __forceinline__ float fast_rcp(float x)  { return __builtin_amdgcn_rcpf(x); }

// fp32 <-> fp16 (RNE)
__device__ __forceinline__ ushort f2h(float x) {
    _Float16 h = (_Float16)x;
    return __builtin_bit_cast(ushort, h);
}
__device__ __forceinline__ float h2f(ushort u) {
    return (float)__builtin_bit_cast(_Float16, u);
}

// async global->LDS, 16 bytes/lane; LDS dest = wave-uniform base + lane*16.
__device__ __forceinline__ void gload16(const ushort* g, ushort* l) {
    __builtin_amdgcn_global_load_lds(
        (const __attribute__((address_space(1))) void*)g,
        (__attribute__((address_space(3))) void*)l, 16, 0, 0);
}

// Pre-swizzled-source staging (round-10/13 proven).
#define GL_DEFS                                                                \
    const int lane8 = lane >> 3;                                               \
    const int scol  = (lane & 7) ^ lane8;                                      \
    const int wq    = wave * 8;

#define STAGE_GL(SRC, DST, BASE, LDK, KOFF)                                    \
    _Pragma("unroll")                                                          \
    for (int q = 0; q < 4; ++q) {                                              \
        const int rr = q * 32 + wq + lane8;                                    \
        gload16(&SRC[(size_t)((BASE) + rr) * (LDK) + (KOFF) + scol * 8],       \
                ((ushort*)DST) + (q * 256 + wave * 64) * 8);                   \
    }

// fp16 2-pass inner compute for one 32-K slice (ks = 0/1).
#define COMPUTE_KS(KS)                                                         \
    {                                                                          \
        const int slot = ((((KS) << 2) | l4) ^ sw) * 8;                        \
        f16x8 ah[4], al[4], bb[4];                                             \
        _Pragma("unroll")                                                      \
        for (int f = 0; f < 4; ++f) {                                          \
            const int ar = mw + f * 16 + l15;                                  \
            const int br = nw + f * 16 + l15;                                  \
            ah[f] = *(const f16x8*)&lA[0][ar][slot];                           \
            al[f] = *(const f16x8*)&lA[1][ar][slot];                           \
            bb[f] = *(const f16x8*)&lB[br][slot];                              \
        }                                                                      \
        _Pragma("unroll")                                                      \
        for (int i = 0; i < 4; ++i)                                            \
            _Pragma("unroll")                                                  \
            for (int j = 0; j < 4; ++j) {                                      \
                acc[i][j] = __builtin_amdgcn_mfma_f32_16x16x32_f16(            \
                    ah[i], bb[j], acc[i][j], 0, 0, 0);                         \
                acc[i][j] = __builtin_amdgcn_mfma_f32_16x16x32_f16(            \
                    al[i], bb[j], acc[i][j], 0, 0, 0);                         \
            }                                                                  \
    }

// v_add_f32 with DPP-moved operand.
template <int CTRL>
__device__ __forceinline__ float dpp_add(float x) {
    int y = __builtin_amdgcn_update_dpp(0, __float_as_int(x), CTRL, 0xF, 0xF, true);
    return x + __int_as_float(y);
}

// ---------------------------------------------------------------------------
// split fp32 -> fp16 hi/lo (elementwise). One float4 per thread.
// ---------------------------------------------------------------------------
__global__ __launch_bounds__(256) void split_f16(
    const float* __restrict__ in, ushort* __restrict__ hi,
    ushort* __restrict__ lo)
{
    const int i = blockIdx.x * 256 + threadIdx.x;
    const float4 v = *(const float4*)&in[(size_t)i * 4];
    ushort4 h, l;
    h.x = f2h(v.x); l.x = f2h(v.x - h2f(h.x));
    h.y = f2h(v.y); l.y = f2h(v.y - h2f(h.y));
    h.z = f2h(v.z); l.z = f2h(v.z - h2f(h.z));
    h.w = f2h(v.w); l.w = f2h(v.w - h2f(h.w));
    *(ushort4*)&hi[(size_t)i * 4] = h;
    *(ushort4*)&lo[(size_t)i * 4] = l;
}

// ---------------------------------------------------------------------------
// transpose + fp16 convert: in[R][C] fp32 -> out[C][R] fp16.
// ---------------------------------------------------------------------------
__global__ __launch_bounds__(256) void trans_f16(
    const float* __restrict__ in, ushort* __restrict__ out, int R, int C)
{
    __shared__ float tile[32][33];
    const int c0 = blockIdx.x * 32;
    const int r0 = blockIdx.y * 32;
    const int tc = threadIdx.x & 31;
    const int tr = threadIdx.x >> 5;
#pragma unroll
    for (int q = 0; q < 4; ++q)
        tile[tr + 8 * q][tc] = in[(size_t)(r0 + tr + 8 * q) * C + c0 + tc];
    __syncthreads();
#pragma unroll
    for (int q = 0; q < 4; ++q)
        out[(size_t)(c0 + tr + 8 * q) * R + r0 + tc] = f2h(tile[tc][tr + 8 * q]);
}

__global__ __launch_bounds__(256) void trans_f16_pad(
    const float* __restrict__ in, ushort* __restrict__ out, int R, int Csrc)
{
    __shared__ float tile[32][33];
    const int c0 = blockIdx.x * 32;
    const int r0 = blockIdx.y * 32;
    const int tc = threadIdx.x & 31;
    const int tr = threadIdx.x >> 5;
#pragma unroll
    for (int q = 0; q < 4; ++q) {
        const int c = c0 + tc;
        tile[tr + 8 * q][tc] =
            (c < Csrc) ? in[(size_t)(r0 + tr + 8 * q) * Csrc + c] : 0.f;
    }
    __syncthreads();
#pragma unroll
    for (int q = 0; q < 4; ++q)
        out[(size_t)(c0 + tr + 8 * q) * R + r0 + tc] = f2h(tile[tc][tr + 8 * q]);
}

// ---------------------------------------------------------------------------
// fp16 2-pass MFMA GEMM (round-13 proven). C1 epilogue applies SiLU gate.
// ---------------------------------------------------------------------------
__global__ __launch_bounds__(256) void gemm_mfma3(
    const ushort* __restrict__ Ahi, const ushort* __restrict__ Alo,
    const ushort* __restrict__ Bf,
    float* __restrict__ C0, float* __restrict__ C1, int nsplit,
    int M, int N, int K, int ldc0, int ldc1)
{
    __shared__ ushort lA[2][128][64];   // 32 KB
    __shared__ ushort lB[128][64];      // 16 KB

    const int t    = threadIdx.x;
    const int m0   = blockIdx.y * 128;
    const int n0   = blockIdx.x * 128;
    const int wave = t >> 6;
    const int lane = t & 63;
    const int mw   = (wave & 1) * 64;
    const int nw   = (wave >> 1) * 64;
    const int l15  = lane & 15;
    const int l4   = lane >> 4;
    const int sw   = l15 & 7;
    GL_DEFS

    f32x4 acc[4][4];
#pragma unroll
    for (int i = 0; i < 4; ++i)
#pragma unroll
        for (int j = 0; j < 4; ++j)
            acc[i][j] = (f32x4){0.f, 0.f, 0.f, 0.f};

    for (int k0 = 0; k0 < K; k0 += 64) {
        __syncthreads();
        STAGE_GL(Ahi, lA[0], m0, K, k0)
        STAGE_GL(Alo, lA[1], m0, K, k0)
        STAGE_GL(Bf,  lB,    n0, K, k0)
        __syncthreads();
        COMPUTE_KS(0)
        COMPUTE_KS(1)
    }

#pragma unroll
    for (int i = 0; i < 4; ++i) {
        const int rowg = m0 + mw + i * 16 + l4 * 4;
#pragma unroll
        for (int j = 0; j < 4; ++j) {
            const int colg = n0 + nw + j * 16 + l15;
            if (colg < nsplit) {
#pragma unroll
                for (int v = 0; v < 4; ++v)
                    C0[(size_t)(rowg + v) * ldc0 + colg] = acc[i][j][v];
            } else {
                const int cc = colg - nsplit;
#pragma unroll
                for (int v = 0; v < 4; ++v) {
                    const float r = acc[i][j][v];
                    C1[(size_t)(rowg + v) * ldc1 + cc] =
                        r * fast_rcp(1.f + fast_exp2(-LOG2E * r));
                }
            }
        }
    }
}

// ---------------------------------------------------------------------------
// split-K MFMA GEMM for x_dbl = u @ W_x (N padded 96->128), fp16 2-pass.
// ---------------------------------------------------------------------------
__global__ __launch_bounds__(256) void gemm_wx_mfma(
    const ushort* __restrict__ Ahi, const ushort* __restrict__ Alo,
    const ushort* __restrict__ Bf, float* __restrict__ part)
{
    __shared__ ushort lA[2][128][64];
    __shared__ ushort lB[128][64];

    const int t    = threadIdx.x;
    const int kb   = blockIdx.x;
    const int m0   = blockIdx.y * 128;
    const int wave = t >> 6;
    const int lane = t & 63;
    const int mw   = (wave & 1) * 64;
    const int nw   = (wave >> 1) * 64;
    const int l15  = lane & 15;
    const int l4   = lane >> 4;
    const int sw   = l15 & 7;
    const int kbase = kb * WX_KSEG;
    GL_DEFS

    f32x4 acc[4][4];
#pragma unroll
    for (int i = 0; i < 4; ++i)
#pragma unroll
        for (int j = 0; j < 4; ++j)
            acc[i][j] = (f32x4){0.f, 0.f, 0.f, 0.f};

    for (int k0 = 0; k0 < WX_KSEG; k0 += 64) {
        __syncthreads();
        STAGE_GL(Ahi, lA[0], m0, D_IN, kbase + k0)
        STAGE_GL(Alo, lA[1], m0, D_IN, kbase + k0)
        STAGE_GL(Bf,  lB,    0,  D_IN, kbase + k0)
        __syncthreads();
        COMPUTE_KS(0)
        COMPUTE_KS(1)
    }

#pragma unroll
    for (int i = 0; i < 4; ++i) {
        const int rowg = m0 + mw + i * 16 + l4 * 4;
#pragma unroll
        for (int j = 0; j < 4; ++j) {
            const int colg = nw + j * 16 + l15;
#pragma unroll
            for (int v = 0; v < 4; ++v)
                part[((size_t)kb * SEQ + rowg + v) * XDBL_LD + colg] =
                    acc[i][j][v];
        }
    }
}

// Fixed-order reduction of the WX_KSPLIT partials -> xdbl [SEQ][XDBL_LD].
__global__ __launch_bounds__(256) void wx_reduce(
    const float* __restrict__ part, float* __restrict__ xdbl)
{
    const size_t i = (size_t)(blockIdx.x * 256 + threadIdx.x) * 4;
    float4 s = *(const float4*)&part[i];
#pragma unroll
    for (int kb = 1; kb < WX_KSPLIT; ++kb) {
        const float4 v = *(const float4*)&part[(size_t)kb * SEQ * XDBL_LD + i];
        s.x += v.x; s.y += v.y; s.z += v.z; s.w += v.w;
    }
    *(float4*)&xdbl[i] = s;
}

// ---------------------------------------------------------------------------
// split-K=4 MFMA GEMM for out = yg @ W_out, fp16 2-pass.
// ---------------------------------------------------------------------------
__global__ __launch_bounds__(256) void gemm_out_mfma(
    const ushort* __restrict__ Ahi, const ushort* __restrict__ Alo,
    const ushort* __restrict__ Bf,
    float* __restrict__ p01, float* __restrict__ p23)
{
    __shared__ ushort lA[2][128][64];
    __shared__ ushort lB[128][64];

    const int t    = threadIdx.x;
    const int n0   = blockIdx.x * 128;
    const int m0   = blockIdx.y * 128;
    const int kb   = blockIdx.z;
    const int wave = t >> 6;
    const int lane = t & 63;
    const int mw   = (wave & 1) * 64;
    const int nw   = (wave >> 1) * 64;
    const int l15  = lane & 15;
    const int l4   = lane >> 4;
    const int sw   = l15 & 7;
    const int kbase = kb * OUT_KSEG;
    GL_DEFS

    f32x4 acc[4][4];
#pragma unroll
    for (int i = 0; i < 4; ++i)
#pragma unroll
        for (int j = 0; j < 4; ++j)
            acc[i][j] = (f32x4){0.f, 0.f, 0.f, 0.f};

    for (int k0 = 0; k0 < OUT_KSEG; k0 += 64) {
        __syncthreads();
        STAGE_GL(Ahi, lA[0], m0, D_IN, kbase + k0)
        STAGE_GL(Alo, lA[1], m0, D_IN, kbase + k0)
        STAGE_GL(Bf,  lB,    n0, D_IN, kbase + k0)
        __syncthreads();
        COMPUTE_KS(0)
        COMPUTE_KS(1)
    }

    float* base = (kb & 2) ? p23 : p01;
    base += (size_t)(kb & 1) * SEQ * D_MODEL;
#pragma unroll
    for (int i = 0; i < 4; ++i) {
        const int rowg = m0 + mw + i * 16 + l4 * 4;
#pragma unroll
        for (int j = 0; j < 4; ++j) {
            const int colg = n0 + nw + j * 16 + l15;
#pragma unroll
            for (int v = 0; v < 4; ++v)
                base[(size_t)(rowg + v) * D_MODEL + colg] = acc[i][j][v];
        }
    }
}

// Fixed-order reduce of the 4 output partials -> out [SEQ][D_MODEL].
__global__ __launch_bounds__(256) void out_reduce(
    const float* __restrict__ p01, const float* __restrict__ p23,
    float* __restrict__ out)
{
    const size_t i = (size_t)(blockIdx.x * 256 + threadIdx.x) * 4;
    const size_t MN = (size_t)SEQ * D_MODEL;
    const float4 a = *(const float4*)&p01[i];
    const float4 b = *(const float4*)&p01[i + MN];
    const float4 c = *(const float4*)&p23[i];
    const float4 d = *(const float4*)&p23[i + MN];
    float4 s;
    s.x = ((a.x + b.x) + c.x) + d.x;
    s.y = ((a.y + b.y) + c.y) + d.y;
    s.z = ((a.z + b.z) + c.z) + d.z;
    s.w = ((a.w + b.w) + c.w) + d.w;
    *(float4*)&out[i] = s;
}

// ---------------------------------------------------------------------------
// fp32 tiled GEMM for delta (K=64) + FUSED per-chunk double column sums.
// Tile 128 rows x 128 cols = exactly 2 chunks x 128 d -> each (chunk,d)
// covered by exactly one block; deterministic 8x8 double tree per column.
// ---------------------------------------------------------------------------
__global__ __launch_bounds__(256) void gemm128(
    const float* __restrict__ A, const float* __restrict__ B,
    float* __restrict__ C, int M, int N, int K,
    int lda, int ldb, int ldc,
    const float* __restrict__ bias, double* __restrict__ csumOut)
{
    __shared__ float As[16][132];
    __shared__ float Bs[16][132];
    __shared__ double dpart[16][128];   // 16 KB

    const int t   = threadIdx.x;
    const int bn0 = blockIdx.x * 128;
    const int bm0 = blockIdx.y * 128;
    const int tx  = t & 15;
    const int ty  = t >> 4;

    const int ar  = t >> 2;
    const int ak  = (t & 3) * 4;
    const int bk  = t >> 5;
    const int bn4 = (t & 31) * 4;

    float acc[8][8];
#pragma unroll
    for (int i = 0; i < 8; ++i)
#pragma unroll
        for (int j = 0; j < 8; ++j) acc[i][j] = 0.f;

    for (int k0 = 0; k0 < K; k0 += 16) {
        float4 a0 = *(const float4*)&A[(size_t)(bm0 + ar)      * lda + k0 + ak];
        float4 a1 = *(const float4*)&A[(size_t)(bm0 + ar + 64) * lda + k0 + ak];
        float4 b0 = *(const float4*)&B[(size_t)(k0 + bk)     * ldb + bn0 + bn4];
        float4 b1 = *(const float4*)&B[(size_t)(k0 + bk + 8) * ldb + bn0 + bn4];

        __syncthreads();
        As[ak + 0][ar] = a0.x; As[ak + 1][ar] = a0.y;
        As[ak + 2][ar] = a0.z; As[ak + 3][ar] = a0.w;
        As[ak + 0][ar + 64] = a1.x; As[ak + 1][ar + 64] = a1.y;
        As[ak + 2][ar + 64] = a1.z; As[ak + 3][ar + 64] = a1.w;
        *(float4*)&Bs[bk][bn4]     = b0;
        *(float4*)&Bs[bk + 8][bn4] = b1;
        __syncthreads();

#pragma unroll
        for (int kk = 0; kk < 16; ++kk) {
            float a[8], b[8];
            ((float4*)a)[0] = *(const float4*)&As[kk][ty * 8];
            ((float4*)a)[1] = *(const float4*)&As[kk][ty * 8 + 4];
            ((float4*)b)[0] = *(const float4*)&Bs[kk][tx * 8];
            ((float4*)b)[1] = *(const float4*)&Bs[kk][tx * 8 + 4];
#pragma unroll
            for (int i = 0; i < 8; ++i)
#pragma unroll
                for (int j = 0; j < 8; ++j)
                    acc[i][j] = fmaf(a[i], b[j], acc[i][j]);
        }
    }

    const int row = bm0 + ty * 8;
    const int col = bn0 + tx * 8;
    double dsum[8];
#pragma unroll
    for (int j = 0; j < 8; ++j) dsum[j] = 0.0;
#pragma unroll
    for (int i = 0; i < 8; ++i) {
        float vals[8];
#pragma unroll
        for (int j = 0; j < 8; ++j) {
            float v = acc[i][j] + bias[col + j];
            v = (v > 20.f) ? v : log1pf(__expf(v));   // softplus
            vals[j] = v;
            dsum[j] += (double)v;
        }
        *(float4*)&C[(size_t)(row + i) * ldc + col]     = ((float4*)vals)[0];
        *(float4*)&C[(size_t)(row + i) * ldc + col + 4] = ((float4*)vals)[1];
    }

    // per-chunk double column sums: ty 0..7 -> chunk 0, ty 8..15 -> chunk 1
#pragma unroll
    for (int j = 0; j < 8; ++j) dpart[ty][tx * 8 + j] = dsum[j];
    __syncthreads();
    {
        const int colr = t & 127;
        const int half = t >> 7;
        double s = 0.0;
#pragma unroll
        for (int q = 0; q < 8; ++q) s += dpart[half * 8 + q][colr];
        csumOut[(size_t)((bm0 >> 6) + half) * D_IN + bn0 + colr] = s;
    }
}

// ---------------------------------------------------------------------------
// Depthwise causal conv (K=3) + SiLU, fused with fp16 hi/lo split of u.
// ---------------------------------------------------------------------------
__global__ __launch_bounds__(256) void conv_silu_split(
    const float* __restrict__ xi, const float* __restrict__ cw,
    float* __restrict__ u, ushort* __restrict__ uhi, ushort* __restrict__ ulo)
{
    const int id = blockIdx.x * 256 + threadIdx.x;
    const int l = id >> 11;
    const int d = id & (D_IN - 1);
    const float w0 = cw[d * 3 + 0];
    const float w1 = cw[d * 3 + 1];
    const float w2 = cw[d * 3 + 2];
    const float x0  = xi[(size_t)l * D_IN + d];
    const float xm1 = (l >= 1) ? xi[(size_t)(l - 1) * D_IN + d] : 0.f;
    const float xm2 = (l >= 2) ? xi[(size_t)(l - 2) * D_IN + d] : 0.f;
    const float v = w0 * xm2 + w1 * xm1 + w2 * x0;
    const float s = fast_rcp(1.f + fast_exp2(-LOG2E * v));
    const float uu = v * s;
    u[id] = uu;
    const ushort h = f2h(uu);
    uhi[id] = h;
    ulo[id] = f2h(uu - h2f(h));
}

// ---------------------------------------------------------------------------
// sfx[l][d] = float(max(Td - P_incl(l), 0)), with the 32-chunk double prefix
// inlined (serial order identical to the old chunk_prefix).
// ---------------------------------------------------------------------------
__global__ __launch_bounds__(256) void sfx_precompute(
    const float* __restrict__ delta, const double* __restrict__ csum,
    float* __restrict__ sfx)
{
    const int d = blockIdx.x * 256 + threadIdx.x;
    const int c = blockIdx.y;
    double S = 0.0, P = 0.0;
    for (int c2 = 0; c2 < NCH; ++c2) {
        if (c2 == c) P = S;
        S += csum[(size_t)c2 * D_IN + d];
    }
    const double T = S;
    for (int i = 0; i < LC; ++i) {
        const size_t row = (size_t)(c * LC + i) * D_IN + d;
        P += (double)delta[row];
        sfx[row] = (float)fmax(T - P, 0.0);
    }
}

// ---------------------------------------------------------------------------
// Pass A (cumsum form), 2 states/lane: block = 256 thr = 32 d x 8 n-lanes.
// Wc[c,d,n] = sum_j du[j]*B[j,n]*exp2(An2*sfx[j]) for n in {n8, n8+8}.
// ---------------------------------------------------------------------------
__global__ __launch_bounds__(256) void scan_partA(
    const float* __restrict__ delta, const float* __restrict__ u,
    const float* __restrict__ sfxbuf, const float* __restrict__ xdbl,
    const float* __restrict__ Alog, float* __restrict__ Wc)
{
    __shared__ float2 spA[LC][DT];     // (du, sfx)        16 KB
    __shared__ float2 sbA[LC][8];      // (B[n8], B[n8+8])  4 KB

    const int t  = threadIdx.x;
    const int c  = blockIdx.x;
    const int d0 = blockIdx.y * DT;

#pragma unroll
    for (int q = 0; q < 8; ++q) {
        const int e = q * 256 + t;
        const int r = e >> 5, col = e & 31;
        const size_t row = (size_t)(c * LC + r) * D_IN + d0 + col;
        spA[r][col] = make_float2(delta[row] * u[row], sfxbuf[row]);
    }
#pragma unroll
    for (int q = 0; q < 2; ++q) {
        const int e = q * 256 + t;
        const int r = e >> 3, n8e = e & 7;
        const size_t base = (size_t)(c * LC + r) * XDBL_LD + DT_RANK;
        sbA[r][n8e] = make_float2(xdbl[base + n8e], xdbl[base + 8 + n8e]);
    }
    __syncthreads();

    const int dq = t >> 3;
    const int n8 = t & 7;
    const int d  = d0 + dq;
    const float An2a = -expf(Alog[d * N_STATE + n8]) * LOG2E;
    const float An2b = -expf(Alog[d * N_STATE + n8 + 8]) * LOG2E;

    float W0 = 0.f, W1 = 0.f;
#pragma unroll
    for (int i = 0; i < LC; ++i) {
        const float2 p = spA[i][dq];
        const float2 b = sbA[i][n8];
        W0 = fmaf(p.x * b.x, fast_exp2(An2a * p.y), W0);
        W1 = fmaf(p.x * b.y, fast_exp2(An2b * p.y), W1);
    }
    const size_t o = ((size_t)c * D_IN + d) * N_STATE + n8;
    Wc[o]     = W0;
    Wc[o + 8] = W1;
}

// ---------------------------------------------------------------------------
// Pass B: exclusive prefix over chunks (plain adds; cumsum form).
// ---------------------------------------------------------------------------
__global__ __launch_bounds__(256) void scan_combine(float* __restrict__ Wc)
{
    const int id = blockIdx.x * 256 + threadIdx.x;   // (d,n)
    float W = 0.f;
    for (int c = 0; c < NCH; ++c) {
        const size_t idx = (size_t)c * (D_IN * N_STATE) + id;
        const float w = Wc[idx];
        Wc[idx] = W;
        W += w;
    }
}

// ---------------------------------------------------------------------------
// Pass C (cumsum form), 2 states/lane: block = 256 thr = 32 d x 8 n-lanes.
// Per iter per lane: 2x b128 LDS reads serve 2 elements; reduce = 1 add +
// 3 DPP (xor1, xor2, ror4 within the 8-lane d-group; only n8==0 writes).
// ---------------------------------------------------------------------------
__global__ __launch_bounds__(256) void scan_partC(
    const float* __restrict__ delta, const float* __restrict__ u,
    const float* __restrict__ xdbl, const float* __restrict__ W0buf,
    const float* __restrict__ sfxbuf, const float* __restrict__ Alog,
    const float* __restrict__ Dvec, const float* __restrict__ rgbuf,
    float* __restrict__ yg)
{
    __shared__ float4 spack[LC][DT];   // (du, sfx, u, rg) 32 KB
    __shared__ float4 sbc[LC][8];      // (B[n8],C[n8],B[n8+8],C[n8+8]) 4 KB

    const int t  = threadIdx.x;
    const int c  = blockIdx.x;
    const int d0 = blockIdx.y * DT;

#pragma unroll
    for (int q = 0; q < 8; ++q) {
        const int e = q * 256 + t;
        const int r = e >> 5, col = e & 31;
        const size_t row = (size_t)(c * LC + r) * D_IN + d0 + col;
        const float dv = delta[row];
        const float uv = u[row];
        spack[r][col] = make_float4(dv * uv, sfxbuf[row], uv, rgbuf[row]);
    }
#pragma unroll
    for (int q = 0; q < 2; ++q) {
        const int e = q * 256 + t;
        const int r = e >> 3, n8e = e & 7;
        const size_t base = (size_t)(c * LC + r) * XDBL_LD + DT_RANK;
        sbc[r][n8e] = make_float4(xdbl[base + n8e],      xdbl[base + 16 + n8e],
                                  xdbl[base + 8 + n8e],  xdbl[base + 24 + n8e]);
    }
    __syncthreads();

    const int dq = t >> 3;
    const int n8 = t & 7;
    const int d  = d0 + dq;
    const float An2a = -expf(Alog[d * N_STATE + n8]) * LOG2E;
    const float An2b = -expf(Alog[d * N_STATE + n8 + 8]) * LOG2E;
    const float Dd = Dvec[d];

    const size_t wo = ((size_t)c * D_IN + d) * N_STATE + n8;
    float W0 = W0buf[wo];
    float W1 = W0buf[wo + 8];

#pragma unroll
    for (int i = 0; i < LC; ++i) {
        const float4 p  = spack[i][dq];
        const float4 bc = sbc[i][n8];
        const float E0 = fast_exp2(An2a * p.y);
        const float E1 = fast_exp2(An2b * p.y);
        W0 = fmaf(p.x * bc.x, E0, W0);
        W1 = fmaf(p.x * bc.z, E1, W1);
        const float xs0 = W0 * fast_rcp(E0 + 1e-12f);
        const float xs1 = W1 * fast_rcp(E1 + 1e-12f);
        float contrib = fmaf(xs0, bc.y, xs1 * bc.w);
        contrib = dpp_add<0xB1>(contrib);    // quad_perm 1,0,3,2  (xor 1)
        contrib = dpp_add<0x4E>(contrib);    // quad_perm 2,3,0,1  (xor 2)
        contrib = dpp_add<0x124>(contrib);   // row_ror:4 (lane k <- k+4)
        if (n8 == 0) {
            yg[(size_t)(c * LC + i) * D_IN + d] =
                fmaf(p.z, Dd, contrib) * p.w;
        }
    }
}

// ---------------------------------------------------------------------------
// Launch.  Workspace (74.5 MB peak, time-multiplexed; ws proven >= 84.9 MB):
//   [ 0    ,16.78M): xi -> wxp -> sfx -> yg_hi/yg_lo
//   [16.78 ,33.55 ): rg (gemm1 epilogue) -> out partials p01
//   [33.55 ,50.33 ): x_hi/x_lo -> u (f32) -> wo (fp16)
//   [50.33 ,51.38 ): xdbl [2048][128] f32
//   [51.38 ,68.16 ): wi (fp16) -> u_hi/u_lo -> delta/yg -> p23
//   [68.16 ,73.42 ): Wc/W0, csum
//   [73.42 ,74.47 ): wx (fp16)
// ---------------------------------------------------------------------------
extern "C" void kernel_launch(void* const* d_in, const int* in_sizes, int n_in,
                              void* d_out, int out_size, void* d_ws, size_t ws_size,
                              hipStream_t stream)
{
    const float* x      = (const float*)d_in[0];
    const float* W_in   = (const float*)d_in[1];
    const float* conv_w = (const float*)d_in[2];
    const float* W_x    = (const float*)d_in[3];
    const float* W_del  = (const float*)d_in[4];
    const float* b_del  = (const float*)d_in[5];
    const float* A_log  = (const float*)d_in[6];
    const float* Dv     = (const float*)d_in[7];
    const float* W_out  = (const float*)d_in[8];
    float* out = (float*)d_out;

    char* ws = (char*)d_ws;
    float*  xi    = (float*)(ws + 0);
    float*  wxp   = (float*)(ws + 0);
    float*  sfx   = (float*)(ws + 0);
    ushort* yg_hi = (ushort*)(ws + 0);
    ushort* yg_lo = (ushort*)(ws + 8388608);
    float*  rg    = (float*)(ws + 16777216);   // gemm1 epilogue: res*sigmoid(res)
    float*  p01   = (float*)(ws + 16777216);
    ushort* x_hi  = (ushort*)(ws + 33554432);
    ushort* x_lo  = (ushort*)(ws + 37748736);
    float*  u     = (float*)(ws + 33554432);
    ushort* wo    = (ushort*)(ws + 33554432);  // [1024][2048] fp16
    float*  xdbl  = (float*)(ws + 50331648);
    ushort* wi    = (ushort*)(ws + 51380224);  // [4096][1024] fp16
    ushort* u_hi  = (ushort*)(ws + 51380224);
    ushort* u_lo  = (ushort*)(ws + 59768832);
    float*  delta = (float*)(ws + 51380224);
    float*  p23   = (float*)(ws + 51380224);
    float*  Wc    = (float*)(ws + 68157440);   // 4.19 MB
    double* csum  = (double*)(ws + 72351744);  // 0.52 MB
    ushort* wx    = (ushort*)(ws + 73416704);  // [128][2048] fp16
    float*  yg    = delta;

    // 1) W_in^T -> fp16
    trans_f16<<<dim3(4096 / 32, 1024 / 32), 256, 0, stream>>>(
        W_in, wi, 1024, 4096);

    // 2) x -> fp16 hi/lo
    split_f16<<<(SEQ * D_MODEL / 4) / 256, 256, 0, stream>>>(x, x_hi, x_lo);

    // 3) [xi | rg] = x @ W_in   (fp16 2-pass; C1 applies SiLU gate)
    gemm_mfma3<<<dim3(4096 / 128, 2048 / 128), 256, 0, stream>>>(
        x_hi, x_lo, wi, xi, rg, D_IN,
        SEQ, 2 * D_IN, D_MODEL, D_IN, D_IN);

    // 4) u = silu(conv(xi)) + u fp16 hi/lo (fused)
    conv_silu_split<<<(SEQ * D_IN) / 256, 256, 0, stream>>>(
        xi, conv_w, u, u_hi, u_lo);

    // 5) W_x^T padded -> fp16
    trans_f16_pad<<<dim3(XDBL_LD / 32, D_IN / 32), 256, 0, stream>>>(
        W_x, wx, D_IN, XDBL_W);

    // 6) x_dbl = u @ W_x  (split-K fp16 2-pass, fixed-order reduce)
    gemm_wx_mfma<<<dim3(WX_KSPLIT, SEQ / 128), 256, 0, stream>>>(
        u_hi, u_lo, wx, wxp);
    wx_reduce<<<(SEQ * XDBL_LD / 4) / 256, 256, 0, stream>>>(wxp, xdbl);

    // 7) delta = softplus(...) + fused per-chunk double column sums
    gemm128<<<dim3(2048 / 128, 2048 / 128), 256, 0, stream>>>(
        xdbl, W_del, delta, SEQ, D_IN, DT_RANK, XDBL_LD, D_IN, D_IN,
        b_del, csum);

    // 8) suffix precompute (inline 32-chunk double prefix)
    sfx_precompute<<<dim3(D_IN / 256, NCH), 256, 0, stream>>>(delta, csum, sfx);

    // 9) chunk-parallel scan (cumsum form, 2 states/lane)
    scan_partA<<<dim3(NCH, D_IN / DT), 256, 0, stream>>>(
        delta, u, sfx, xdbl, A_log, Wc);
    scan_combine<<<(D_IN * N_STATE) / 256, 256, 0, stream>>>(Wc);
    scan_partC<<<dim3(NCH, D_IN / DT), 256, 0, stream>>>(
        delta, u, xdbl, Wc, sfx, A_log, Dv, rg, yg);

    // 10) yg -> fp16 hi/lo (sfx dead; region reused)
    split_f16<<<(SEQ * D_IN / 4) / 256, 256, 0, stream>>>(yg, yg_hi, yg_lo);

    // 11) W_out^T -> fp16 (u dead; region reused)
    trans_f16<<<dim3(1024 / 32, 2048 / 32), 256, 0, stream>>>(
        W_out, wo, 2048, 1024);

    // 12) out = yg @ W_out  (split-K=4 fp16 2-pass; partials in dead regions)
    gemm_out_mfma<<<dim3(D_MODEL / 128, SEQ / 128, OUT_KSPLIT), 256, 0, stream>>>(
        yg_hi, yg_lo, wo, p01, p23);
    out_reduce<<<(SEQ * D_MODEL / 4) / 256, 256, 0, stream>>>(p01, p23, out);
}